// Round 2
// baseline (10749.578 us; speedup 1.0000x reference)
//
#include <hip/hip_runtime.h>
#include <hip/hip_bf16.h>

typedef __hip_bfloat16 bf16;

__device__ __forceinline__ float b2f(bf16 x) { return __bfloat162float(x); }

constexpr int Bc = 4, Tc = 1024, Dc = 512, Hc = 8, HDc = 64;
constexpr int LCc = 128, MPc = 192;
constexpr float EPSc = 1e-4f;
constexpr int NBT = Bc * Tc;                 // 4096 rows
constexpr long NE = (long)NBT * Dc;          // 2,097,152 elements
constexpr float NEGB = -1e30f;               // finite mask sentinel (exp -> 0, no inf math)

// flag-dispatched load: f32flag ? float : bf16, element index i
__device__ __forceinline__ float wload(const void* p, long i, int f32) {
  return f32 ? ((const float*)p)[i] : b2f(((const bf16*)p)[i]);
}

// ---------------- dtype detector: bf16 vs f32 inputs ----------------
// Interpret first 2048 uint16 of x as bf16. Genuine bf16 N(0,1): exponents in
// a narrow band. f32-misread: ~half the uint16s are mantissa garbage with
// uniform exponents -> hundreds of out-of-range values.
__global__ void k_detect(const void* __restrict__ x, int* __restrict__ flag) {
  __shared__ int s[256];
  int t = threadIdx.x;
  const unsigned short* u = (const unsigned short*)x;
  int bad = 0;
  for (int j = t; j < 2048; j += 256) {
    int e = (u[j] >> 7) & 0xFF;                    // bf16 exponent field
    if (e == 0xFF || e > 0x8F || (e != 0 && e < 0x6F)) bad++;
  }
  s[t] = bad;
  __syncthreads();
  for (int off = 128; off > 0; off >>= 1) { if (t < off) s[t] += s[t + off]; __syncthreads(); }
  if (t == 0) flag[0] = (s[0] > 16) ? 1 : 0;
}

// ---------------- input/output converts (flag-dispatched) ----------------
__global__ void k_in(const void* __restrict__ in, float* __restrict__ out, int n,
                     const int* __restrict__ flag) {
  int i = blockIdx.x * 256 + threadIdx.x;
  if (i < n) out[i] = wload(in, i, flag[0]);
}
__global__ void k_out(const float* __restrict__ in, void* __restrict__ out, int n,
                      const int* __restrict__ flag) {
  int i = blockIdx.x * 256 + threadIdx.x;
  if (i >= n) return;
  if (flag[0]) ((float*)out)[i] = in[i];
  else         ((bf16*)out)[i] = __float2bfloat16(in[i]);
}

// ---------------- LayerNorm: one block per row, D=512 ----------------
__global__ __launch_bounds__(256) void k_ln(const float* __restrict__ x,
    const void* __restrict__ w, const void* __restrict__ bb, long woff,
    float* __restrict__ o, const int* __restrict__ flag) {
  int f32 = flag[0];
  int row = blockIdx.x;
  int t = threadIdx.x;
  const float* xr = x + (long)row * Dc;
  float x0 = xr[t], x1 = xr[t + 256];
  __shared__ float red[256];
  red[t] = x0 + x1;
  __syncthreads();
  for (int off = 128; off > 0; off >>= 1) { if (t < off) red[t] += red[t + off]; __syncthreads(); }
  float mean = red[0] * (1.0f / Dc);
  __syncthreads();
  float d0 = x0 - mean, d1 = x1 - mean;
  red[t] = d0 * d0 + d1 * d1;
  __syncthreads();
  for (int off = 128; off > 0; off >>= 1) { if (t < off) red[t] += red[t + off]; __syncthreads(); }
  float inv = 1.0f / sqrtf(red[0] * (1.0f / Dc) + EPSc);
  float* orow = o + (long)row * Dc;
  orow[t]       = d0 * inv * wload(w, woff + t, f32)       + wload(bb, woff + t, f32);
  orow[t + 256] = d1 * inv * wload(w, woff + t + 256, f32) + wload(bb, woff + t + 256, f32);
}

// ---------------- GEMM: C[M,N] = alpha * A[M,K](f32,lda) @ W[N,K]^T (+ addend) ----------------
// BM=BN=64, BK=16, 256 threads, 4x4 micro-tile per thread. M%64==0, N%64==0, K%16==0.
__global__ __launch_bounds__(256) void k_gemm(const float* __restrict__ A, int lda,
    const void* __restrict__ W, long woff, float* __restrict__ C, int ldc,
    const float* __restrict__ addend, float alpha, int M, int N, int K,
    const int* __restrict__ flag) {
  int f32 = flag[0];
  __shared__ float As[16][64];
  __shared__ float Ws[16][64];
  int tid = threadIdx.x;
  int m0 = blockIdx.y * 64, n0 = blockIdx.x * 64;
  int tx = tid & 15, ty = tid >> 4;
  int lr = tid >> 2;            // 0..63
  int lk = (tid & 3) * 4;       // 0,4,8,12
  float acc[4][4] = {};
  for (int k0 = 0; k0 < K; k0 += 16) {
    const float* Ap = A + (long)(m0 + lr) * lda + k0 + lk;
    long wbase = woff + (long)(n0 + lr) * K + k0 + lk;
#pragma unroll
    for (int u = 0; u < 4; ++u) As[lk + u][lr] = Ap[u];
#pragma unroll
    for (int u = 0; u < 4; ++u) Ws[lk + u][lr] = wload(W, wbase + u, f32);
    __syncthreads();
#pragma unroll
    for (int kk = 0; kk < 16; ++kk) {
      float a_[4], b_[4];
#pragma unroll
      for (int i = 0; i < 4; ++i) a_[i] = As[kk][ty * 4 + i];
#pragma unroll
      for (int j = 0; j < 4; ++j) b_[j] = Ws[kk][tx * 4 + j];
#pragma unroll
      for (int i = 0; i < 4; ++i)
#pragma unroll
        for (int j = 0; j < 4; ++j) acc[i][j] += a_[i] * b_[j];
    }
    __syncthreads();
  }
#pragma unroll
  for (int i = 0; i < 4; ++i) {
    int m = m0 + ty * 4 + i;
#pragma unroll
    for (int j = 0; j < 4; ++j) {
      int n = n0 + tx * 4 + j;
      float v = alpha * acc[i][j];
      if (addend) v += addend[(long)m * ldc + n];
      C[(long)m * ldc + n] = v;
    }
  }
}

// ---------------- Attention: one block per (b, h, qo) ----------------
__global__ __launch_bounds__(256) void k_attn(const float* __restrict__ q,
    const float* __restrict__ kbuf, const float* __restrict__ vbuf,
    const void* __restrict__ rel, long roff, const int* __restrict__ alen,
    float* __restrict__ out, const int* __restrict__ flag) {
  int f32 = flag[0];
  int qo = blockIdx.x, h = blockIdx.y, b = blockIdx.z;
  int g = h >> 2;   // REP = 4
  int len = alen[b];
  int tid = threadIdx.x;
  __shared__ float qs[HDc];
  __shared__ float sc[Tc + LCc];     // up to 1152 scores
  __shared__ float red[256];
  __shared__ float pacc[4][HDc];
  if (tid < HDc) qs[tid] = q[(long)(b * Tc + qo) * Dc + h * HDc + tid];
  __syncthreads();
  bool vq = qo < len;
  int lo, hi;
  if (vq) { int c = (qo >> 6) << 6; lo = c - LCc; hi = c + 64; }
  else    { lo = -LCc; hi = Tc; }
  int nk = hi - lo;
  for (int idx = tid; idx < nk; idx += 256) {
    int ko = lo + idx;
    float s;
    if (vq && ko >= len) {
      s = NEGB;                       // ref gives these NEG=-5e4 -> exp underflows to 0
    } else {
      s = 0.0f;
      if (ko >= 0) {
        const float* kr = kbuf + (long)(b * Tc + ko) * 128 + g * HDc;
#pragma unroll
        for (int d = 0; d < HDc; ++d) s += qs[d] * kr[d];
      }
      int dist = qo - ko;
      if (dist > MPc - 1) dist = MPc - 1;
      if (dist < -(MPc - 1)) dist = -(MPc - 1);
      long rb = roff + (long)(dist + MPc - 1) * HDc;
#pragma unroll
      for (int d = 0; d < HDc; ++d) s += qs[d] * wload(rel, rb + d, f32);
    }
    sc[idx] = s;
  }
  __syncthreads();
  // max
  float lm = NEGB;
  for (int idx = tid; idx < nk; idx += 256) lm = fmaxf(lm, sc[idx]);
  red[tid] = lm;
  __syncthreads();
  for (int off = 128; off > 0; off >>= 1) { if (tid < off) red[tid] = fmaxf(red[tid], red[tid + off]); __syncthreads(); }
  float mx = red[0];
  __syncthreads();
  // exp + sum
  float ls = 0.0f;
  for (int idx = tid; idx < nk; idx += 256) { float p = __expf(sc[idx] - mx); sc[idx] = p; ls += p; }
  red[tid] = ls;
  __syncthreads();
  for (int off = 128; off > 0; off >>= 1) { if (tid < off) red[tid] += red[tid + off]; __syncthreads(); }
  float denom = red[0];
  __syncthreads();
  // weighted sum of v
  int d = tid & 63, part = tid >> 6;
  float acc = 0.0f;
  for (int idx = part; idx < nk; idx += 4) {
    int ko = lo + idx;
    if (ko >= 0) acc += sc[idx] * vbuf[(long)(b * Tc + ko) * 128 + g * HDc + d];
  }
  pacc[part][d] = acc;
  __syncthreads();
  if (tid < HDc) {
    float o = (pacc[0][tid] + pacc[1][tid] + pacc[2][tid] + pacc[3][tid]) / denom;
    out[(long)(b * Tc + qo) * Dc + h * HDc + tid] = o;
  }
}

// ---------------- conv GLU: in-place, rows of 1024 -> first 512 = a * sigmoid(g) ----------------
__global__ void k_glu_conv(float* __restrict__ h, int n) {  // n = B*T*512
  int i = blockIdx.x * 256 + threadIdx.x;
  if (i >= n) return;
  int r = i >> 9, j = i & 511;
  float a = h[(long)r * 1024 + j], g = h[(long)r * 1024 + 512 + j];
  h[(long)r * 1024 + j] = a * (1.0f / (1.0f + __expf(-g)));
}

// ---------------- FFN SwiGLU: in-place, rows of 2048 -> first 1024 = silu(a) * b ----------------
__global__ void k_swiglu(float* __restrict__ h, int n) {    // n = B*T*1024
  int i = blockIdx.x * 256 + threadIdx.x;
  if (i >= n) return;
  int r = i >> 10, j = i & 1023;
  float a = h[(long)r * 2048 + j], bb = h[(long)r * 2048 + 1024 + j];
  h[(long)r * 2048 + j] = (a / (1.0f + __expf(-a))) * bb;
}

// ---------------- depthwise conv(9, pad 4) + silu; in stride 1024, out stride 512 ----------------
__global__ void k_dwconv(const float* __restrict__ in, const void* __restrict__ dw, long doff,
                         float* __restrict__ out, int n, const int* __restrict__ flag) {
  int f32 = flag[0];
  int i = blockIdx.x * 256 + threadIdx.x;
  if (i >= n) return;
  int d = i & 511;
  int t = (i >> 9) & (Tc - 1);
  int b = i >> 19;
  float acc = 0.0f;
#pragma unroll
  for (int j = 0; j < 9; ++j) {
    int tt = t + j - 4;
    if (tt >= 0 && tt < Tc) acc += in[((long)(b * Tc + tt) << 10) + d] * wload(dw, doff + d * 9 + j, f32);
  }
  out[i] = acc * (1.0f / (1.0f + __expf(-acc)));            // silu
}

extern "C" void kernel_launch(void* const* d_in, const int* in_sizes, int n_in,
                              void* d_out, int out_size, void* d_ws, size_t ws_size,
                              hipStream_t stream) {
  const void* x_in = d_in[0];
  const int*  alen = (const int*)d_in[1];
  const void* ln1w = d_in[2];
  const void* ln1b = d_in[3];
  const void* wq   = d_in[4];
  const void* wk   = d_in[5];
  const void* wv   = d_in[6];
  const void* wo   = d_in[7];
  const void* rel  = d_in[8];
  const void* ln2w = d_in[9];
  const void* ln2b = d_in[10];
  const void* pw1  = d_in[11];
  const void* dwv  = d_in[12];
  const void* pw2  = d_in[13];
  const void* ln3w = d_in[14];
  const void* ln3b = d_in[15];
  const void* w1   = d_in[16];
  const void* w2   = d_in[17];

  int*   flag = (int*)d_ws;
  float* xf  = (float*)((char*)d_ws + 256);   // 2M floats: residual stream
  float* lnb = xf + NE;                       // 2M floats: LN output
  float* big = lnb + NE;                      // 8M floats: phase scratch

  // attention-phase layout inside big
  float* qb = big;                                  // 2M
  float* kb = big + NE;                             // 0.5M
  float* vb = big + NE + (long)NBT * 128;           // 0.5M
  float* ab = big + NE + (long)NBT * 256;           // 2M (attention out)
  // conv-phase: pw1-out big[0..4M) (in-place GLU), dwconv-out:
  float* cb = big + (long)NBT * 1024;               // 2M
  // ffn-phase: big[0..8M), in-place swiglu

  k_detect<<<1, 256, 0, stream>>>(x_in, flag);
  k_in<<<(int)((NE + 255) / 256), 256, 0, stream>>>(x_in, xf, (int)NE, flag);

  for (int i = 0; i < 4; ++i) {
    long oQ = (long)i * Dc * Dc;
    long oKV = (long)i * 128 * Dc;
    long oR = (long)i * (2 * MPc - 1) * HDc;
    long oP1 = (long)i * 1024 * Dc;
    long oDW = (long)i * Dc * 9;
    long oF1 = (long)i * 2048 * Dc;
    long oF2 = (long)i * Dc * 1024;
    long oLN = (long)i * Dc;

    // ---- attention block ----
    k_ln<<<NBT, 256, 0, stream>>>(xf, ln1w, ln1b, oLN, lnb, flag);
    k_gemm<<<dim3(8, 64), 256, 0, stream>>>(lnb, Dc, wq, oQ, qb, Dc, nullptr, 0.125f, NBT, Dc, Dc, flag);
    k_gemm<<<dim3(2, 64), 256, 0, stream>>>(lnb, Dc, wk, oKV, kb, 128, nullptr, 1.0f, NBT, 128, Dc, flag);
    k_gemm<<<dim3(2, 64), 256, 0, stream>>>(lnb, Dc, wv, oKV, vb, 128, nullptr, 1.0f, NBT, 128, Dc, flag);
    k_attn<<<dim3(Tc, Hc, Bc), 256, 0, stream>>>(qb, kb, vb, rel, oR, alen, ab, flag);
    k_gemm<<<dim3(8, 64), 256, 0, stream>>>(ab, Dc, wo, oQ, xf, Dc, lnb, 1.0f, NBT, Dc, Dc, flag);

    // ---- conv block ----
    k_ln<<<NBT, 256, 0, stream>>>(xf, ln2w, ln2b, oLN, lnb, flag);
    k_gemm<<<dim3(16, 64), 256, 0, stream>>>(lnb, Dc, pw1, oP1, big, 1024, nullptr, 1.0f, NBT, 1024, Dc, flag);
    k_glu_conv<<<NBT * 512 / 256, 256, 0, stream>>>(big, NBT * 512);
    k_dwconv<<<NBT * 512 / 256, 256, 0, stream>>>(big, dwv, oDW, cb, NBT * 512, flag);
    k_gemm<<<dim3(8, 64), 256, 0, stream>>>(cb, 512, pw2, oQ, xf, Dc, lnb, 1.0f, NBT, Dc, Dc, flag);

    // ---- ffn block ----
    k_ln<<<NBT, 256, 0, stream>>>(xf, ln3w, ln3b, oLN, lnb, flag);
    k_gemm<<<dim3(32, 64), 256, 0, stream>>>(lnb, Dc, w1, oF1, big, 2048, nullptr, 1.0f, NBT, 2048, Dc, flag);
    k_swiglu<<<NBT * 1024 / 256, 256, 0, stream>>>(big, NBT * 1024);
    k_gemm<<<dim3(8, 64), 256, 0, stream>>>(big, 2048, w2, oF2, xf, Dc, lnb, 1.0f, NBT, Dc, 1024, flag);
  }

  k_out<<<(int)((NE + 255) / 256), 256, 0, stream>>>(xf, d_out, (int)NE, flag);
}

// Round 4
// 3914.012 us; speedup vs baseline: 2.7464x; 2.7464x over previous
//
#include <hip/hip_runtime.h>
#include <hip/hip_bf16.h>

typedef __hip_bfloat16 bf16;
typedef unsigned short ushort_t;
typedef unsigned int uint_t;

__device__ __forceinline__ float b2f(bf16 x) { return __bfloat162float(x); }
__device__ __forceinline__ ushort_t f2us(float f) { bf16 h = __float2bfloat16(f); return *(ushort_t*)&h; }
__device__ __forceinline__ float us2f(ushort_t u) { return __uint_as_float(((uint_t)u) << 16); }
__device__ __forceinline__ float lo16(uint_t u) { return __uint_as_float(u << 16); }
__device__ __forceinline__ float hi16(uint_t u) { return __uint_as_float(u & 0xFFFF0000u); }

constexpr int Bc = 4, Tc = 1024, Dc = 512, Hc = 8, HDc = 64;
constexpr int LCc = 128, MPc = 192;
constexpr float EPSc = 1e-4f;
constexpr int NBT = Bc * Tc;                 // 4096 rows
constexpr long NE = (long)NBT * Dc;          // 2,097,152 elements
constexpr float NEGB = -1e30f;

__device__ __forceinline__ float wload(const void* p, long i, int f32) {
  return f32 ? ((const float*)p)[i] : b2f(((const bf16*)p)[i]);
}

// ---------------- dtype detector: bf16 vs f32 inputs ----------------
__global__ void k_detect(const void* __restrict__ x, int* __restrict__ flag) {
  __shared__ int s[256];
  int t = threadIdx.x;
  const unsigned short* u = (const unsigned short*)x;
  int bad = 0;
  for (int j = t; j < 2048; j += 256) {
    int e = (u[j] >> 7) & 0xFF;
    if (e == 0xFF || e > 0x8F || (e != 0 && e < 0x6F)) bad++;
  }
  s[t] = bad;
  __syncthreads();
  for (int off = 128; off > 0; off >>= 1) { if (t < off) s[t] += s[t + off]; __syncthreads(); }
  if (t == 0) flag[0] = (s[0] > 16) ? 1 : 0;
}

__global__ void k_in(const void* __restrict__ in, float* __restrict__ out, int n,
                     const int* __restrict__ flag) {
  int i = blockIdx.x * 256 + threadIdx.x;
  if (i < n) out[i] = wload(in, i, flag[0]);
}
__global__ void k_out(const float* __restrict__ in, void* __restrict__ out, int n,
                      const int* __restrict__ flag) {
  int i = blockIdx.x * 256 + threadIdx.x;
  if (i >= n) return;
  if (flag[0]) ((float*)out)[i] = in[i];
  else         ((bf16*)out)[i] = __float2bfloat16(in[i]);
}

// ---------------- LayerNorm ----------------
__global__ __launch_bounds__(256) void k_ln(const float* __restrict__ x,
    const void* __restrict__ w, const void* __restrict__ bb, long woff,
    float* __restrict__ o, const int* __restrict__ flag) {
  int f32 = flag[0];
  int row = blockIdx.x;
  int t = threadIdx.x;
  const float* xr = x + (long)row * Dc;
  float x0 = xr[t], x1 = xr[t + 256];
  __shared__ float red[256];
  red[t] = x0 + x1;
  __syncthreads();
  for (int off = 128; off > 0; off >>= 1) { if (t < off) red[t] += red[t + off]; __syncthreads(); }
  float mean = red[0] * (1.0f / Dc);
  __syncthreads();
  float d0 = x0 - mean, d1 = x1 - mean;
  red[t] = d0 * d0 + d1 * d1;
  __syncthreads();
  for (int off = 128; off > 0; off >>= 1) { if (t < off) red[t] += red[t + off]; __syncthreads(); }
  float inv = 1.0f / sqrtf(red[0] * (1.0f / Dc) + EPSc);
  float* orow = o + (long)row * Dc;
  orow[t]       = d0 * inv * wload(w, woff + t, f32)       + wload(bb, woff + t, f32);
  orow[t + 256] = d1 * inv * wload(w, woff + t + 256, f32) + wload(bb, woff + t + 256, f32);
}

// ---------------- GEMM: C = alpha*A@W^T (+addend) ----------------
__global__ __launch_bounds__(256) void k_gemm(const float* __restrict__ A, int lda,
    const void* __restrict__ W, long woff, float* __restrict__ C, int ldc,
    const float* __restrict__ addend, float alpha, int M, int N, int K,
    const int* __restrict__ flag) {
  int f32 = flag[0];
  __shared__ float As[16][64];
  __shared__ float Ws[16][64];
  int tid = threadIdx.x;
  int m0 = blockIdx.y * 64, n0 = blockIdx.x * 64;
  int tx = tid & 15, ty = tid >> 4;
  int lr = tid >> 2;
  int lk = (tid & 3) * 4;
  float acc[4][4] = {};
  for (int k0 = 0; k0 < K; k0 += 16) {
    const float* Ap = A + (long)(m0 + lr) * lda + k0 + lk;
    long wbase = woff + (long)(n0 + lr) * K + k0 + lk;
#pragma unroll
    for (int u = 0; u < 4; ++u) As[lk + u][lr] = Ap[u];
#pragma unroll
    for (int u = 0; u < 4; ++u) Ws[lk + u][lr] = wload(W, wbase + u, f32);
    __syncthreads();
#pragma unroll
    for (int kk = 0; kk < 16; ++kk) {
      float a_[4], b_[4];
#pragma unroll
      for (int i = 0; i < 4; ++i) a_[i] = As[kk][ty * 4 + i];
#pragma unroll
      for (int j = 0; j < 4; ++j) b_[j] = Ws[kk][tx * 4 + j];
#pragma unroll
      for (int i = 0; i < 4; ++i)
#pragma unroll
        for (int j = 0; j < 4; ++j) acc[i][j] += a_[i] * b_[j];
    }
    __syncthreads();
  }
#pragma unroll
  for (int i = 0; i < 4; ++i) {
    int m = m0 + ty * 4 + i;
#pragma unroll
    for (int j = 0; j < 4; ++j) {
      int n = n0 + tx * 4 + j;
      float v = alpha * acc[i][j];
      if (addend) v += addend[(long)m * ldc + n];
      C[(long)m * ldc + n] = v;
    }
  }
}

// ---------------- Rq GEMM: Rq[(b*8+h)*1024+qo][384] = q . rel[min(ri,382)] ----------------
__global__ __launch_bounds__(256) void k_rq(const float* __restrict__ qb,
    const void* __restrict__ rel, long roff, bf16* __restrict__ Rq,
    const int* __restrict__ flag) {
  int f32 = flag[0];
  __shared__ float As[16][64];
  __shared__ float Ws[16][64];
  int tid = threadIdx.x;
  int n0 = blockIdx.x * 64;           // ri block (0..383)
  int m0 = blockIdx.y * 64;           // qo block
  int bh = blockIdx.z;                // b*8+h
  int b = bh >> 3, h = bh & 7;
  const float* A = qb + (long)b * Tc * Dc + h * 64;
  int tx = tid & 15, ty = tid >> 4;
  int lr = tid >> 2;
  int lk = (tid & 3) * 4;
  float acc[4][4] = {};
  for (int k0 = 0; k0 < 64; k0 += 16) {
    const float* Ap = A + (long)(m0 + lr) * Dc + k0 + lk;
    int wr = n0 + lr; if (wr > 382) wr = 382;
    long wbase = roff + (long)wr * 64 + k0 + lk;
#pragma unroll
    for (int u = 0; u < 4; ++u) As[lk + u][lr] = Ap[u];
#pragma unroll
    for (int u = 0; u < 4; ++u) Ws[lk + u][lr] = wload(rel, wbase + u, f32);
    __syncthreads();
#pragma unroll
    for (int kk = 0; kk < 16; ++kk) {
      float a_[4], b_[4];
#pragma unroll
      for (int i = 0; i < 4; ++i) a_[i] = As[kk][ty * 4 + i];
#pragma unroll
      for (int j = 0; j < 4; ++j) b_[j] = Ws[kk][tx * 4 + j];
#pragma unroll
      for (int i = 0; i < 4; ++i)
#pragma unroll
        for (int j = 0; j < 4; ++j) acc[i][j] += a_[i] * b_[j];
    }
    __syncthreads();
  }
#pragma unroll
  for (int i = 0; i < 4; ++i) {
    long m = (long)bh * Tc + m0 + ty * 4 + i;
#pragma unroll
    for (int j = 0; j < 4; ++j)
      Rq[m * 384 + n0 + tx * 4 + j] = __float2bfloat16(acc[i][j]);
  }
}

// ---------------- Chunked attention (valid rows): block per (chunk, h, b) ----------------
// 64 queries x 192-key window. Q/K/V staged bf16 in LDS; rel via Rq table.
// P matrix round-trips through LDS as TRANSPOSED bf16 [192][72] overlaying Qt/Kt
// (fixes R3 bug: f32 [64][65] overlay had stride 65 but 192 cols -> row aliasing).
__global__ __launch_bounds__(256) void k_attn_chunk(const float* __restrict__ q,
    const float* __restrict__ kb, const float* __restrict__ vb,
    const bf16* __restrict__ Rq, const int* __restrict__ alen, float* __restrict__ out) {
  int c = blockIdx.x, h = blockIdx.y, b = blockIdx.z;
  int g = h >> 2;
  int len = alen[b];
  int q0 = c * 64;
  if (q0 >= len) return;
  int nvalid = min(len - q0, 64);
  int lo = q0 - 128;
  __shared__ __align__(16) char smem[62464];
  ushort_t* Qt = (ushort_t*)smem;                 // [64][72] (d, qi)
  ushort_t* Kt = (ushort_t*)(smem + 9216);        // [64][200] (d, kj)
  ushort_t* Vs = (ushort_t*)(smem + 34816);       // [192][72] (kj, d)
  ushort_t* Sqt = (ushort_t*)smem;                // [192][72] (kj, qi) overlay after QK
  int t = threadIdx.x;
  int tx = t & 15, ty = t >> 4;
  // ---- stage Q (transpose) ----
#pragma unroll
  for (int p = 0; p < 4; ++p) {
    int qi = p * 16 + ty;
    const float4 v4 = *(const float4*)&q[((long)(b * Tc + q0 + qi)) * Dc + h * 64 + tx * 4];
    Qt[(tx * 4 + 0) * 72 + qi] = f2us(v4.x);
    Qt[(tx * 4 + 1) * 72 + qi] = f2us(v4.y);
    Qt[(tx * 4 + 2) * 72 + qi] = f2us(v4.z);
    Qt[(tx * 4 + 3) * 72 + qi] = f2us(v4.w);
  }
  // ---- stage K (transpose) + V ----
#pragma unroll
  for (int p = 0; p < 12; ++p) {
    int kj = p * 16 + ty;
    int ko = lo + kj;
    float4 kv = make_float4(0.f, 0.f, 0.f, 0.f), vv = kv;
    if (ko >= 0) {
      long base = ((long)(b * Tc + ko)) * 128 + g * 64 + tx * 4;
      kv = *(const float4*)&kb[base];
      vv = *(const float4*)&vb[base];
    }
    Kt[(tx * 4 + 0) * 200 + kj] = f2us(kv.x);
    Kt[(tx * 4 + 1) * 200 + kj] = f2us(kv.y);
    Kt[(tx * 4 + 2) * 200 + kj] = f2us(kv.z);
    Kt[(tx * 4 + 3) * 200 + kj] = f2us(kv.w);
    uint2 P;
    P.x = (uint_t)f2us(vv.x) | ((uint_t)f2us(vv.y) << 16);
    P.y = (uint_t)f2us(vv.z) | ((uint_t)f2us(vv.w) << 16);
    *(uint2*)&Vs[kj * 72 + tx * 4] = P;
  }
  __syncthreads();
  // ---- QK: thread tile 4 qi x 12 kj ----
  int qi0 = ty * 4, kj0 = tx * 12;
  float s[4][12];
#pragma unroll
  for (int i = 0; i < 4; ++i)
#pragma unroll
    for (int j = 0; j < 12; ++j) s[i][j] = 0.f;
  for (int d = 0; d < 64; ++d) {
    uint2 qw = *(const uint2*)&Qt[d * 72 + qi0];
    float qv[4] = {lo16(qw.x), hi16(qw.x), lo16(qw.y), hi16(qw.y)};
    uint2 k0w = *(const uint2*)&Kt[d * 200 + kj0];
    uint2 k1w = *(const uint2*)&Kt[d * 200 + kj0 + 4];
    uint2 k2w = *(const uint2*)&Kt[d * 200 + kj0 + 8];
    float kv[12] = {lo16(k0w.x), hi16(k0w.x), lo16(k0w.y), hi16(k0w.y),
                    lo16(k1w.x), hi16(k1w.x), lo16(k1w.y), hi16(k1w.y),
                    lo16(k2w.x), hi16(k2w.x), lo16(k2w.y), hi16(k2w.y)};
#pragma unroll
    for (int i = 0; i < 4; ++i)
#pragma unroll
      for (int j = 0; j < 12; ++j) s[i][j] += qv[i] * kv[j];
  }
  // ---- add rel (Rq table) + mask ----
  const ushort_t* Rqu = (const ushort_t*)Rq;
  long rqbase = ((long)(b * 8 + h) * Tc + q0 + qi0) * 384;
#pragma unroll
  for (int i = 0; i < 4; ++i) {
#pragma unroll
    for (int j = 0; j < 12; ++j) {
      int ri = (qi0 + i) - (kj0 + j) + 319;       // dist+191, in [128, 382]
      float rv = us2f(Rqu[rqbase + (long)i * 384 + ri]);
      int ko = lo + kj0 + j;
      s[i][j] = (ko >= len) ? NEGB : (s[i][j] + rv);
    }
  }
  // ---- softmax stats (rows shared by 16 lanes: same ty) ----
  float l[4];
#pragma unroll
  for (int i = 0; i < 4; ++i) {
    float mm = s[i][0];
#pragma unroll
    for (int j = 1; j < 12; ++j) mm = fmaxf(mm, s[i][j]);
    for (int o = 1; o < 16; o <<= 1) mm = fmaxf(mm, __shfl_xor(mm, o, 64));
    float ss = 0.f;
#pragma unroll
    for (int j = 0; j < 12; ++j) { s[i][j] = __expf(s[i][j] - mm); ss += s[i][j]; }
    for (int o = 1; o < 16; o <<= 1) ss += __shfl_xor(ss, o, 64);
    l[i] = ss;
  }
  __syncthreads();          // Qt/Kt reads done -> Sqt overlay safe
#pragma unroll
  for (int i = 0; i < 4; ++i)
#pragma unroll
    for (int j = 0; j < 12; ++j) Sqt[(kj0 + j) * 72 + qi0 + i] = f2us(s[i][j]);
  __syncthreads();
  // ---- PV: thread tile 4 qi x 4 d ----
  int d0 = tx * 4;
  float acc[4][4] = {};
  for (int kj = 0; kj < 192; ++kj) {
    uint2 vw = *(const uint2*)&Vs[kj * 72 + d0];
    uint2 pw = *(const uint2*)&Sqt[kj * 72 + qi0];
    float v0 = lo16(vw.x), v1 = hi16(vw.x), v2 = lo16(vw.y), v3 = hi16(vw.y);
    float p0 = lo16(pw.x), p1 = hi16(pw.x), p2 = lo16(pw.y), p3 = hi16(pw.y);
    acc[0][0] += p0 * v0; acc[0][1] += p0 * v1; acc[0][2] += p0 * v2; acc[0][3] += p0 * v3;
    acc[1][0] += p1 * v0; acc[1][1] += p1 * v1; acc[1][2] += p1 * v2; acc[1][3] += p1 * v3;
    acc[2][0] += p2 * v0; acc[2][1] += p2 * v1; acc[2][2] += p2 * v2; acc[2][3] += p2 * v3;
    acc[3][0] += p3 * v0; acc[3][1] += p3 * v1; acc[3][2] += p3 * v2; acc[3][3] += p3 * v3;
  }
#pragma unroll
  for (int i = 0; i < 4; ++i) {
    int qi = qi0 + i;
    if (qi < nvalid) {
      float inv = 1.0f / l[i];
      float4 o4 = make_float4(acc[i][0] * inv, acc[i][1] * inv, acc[i][2] * inv, acc[i][3] * inv);
      *(float4*)&out[((long)(b * Tc + q0 + qi)) * Dc + h * 64 + d0] = o4;
    }
  }
}

// ---------------- Invalid-row attention: flash over 18 key tiles ----------------
__global__ __launch_bounds__(256) void k_attn_inv(const float* __restrict__ q,
    const float* __restrict__ kb, const float* __restrict__ vb,
    const bf16* __restrict__ Rq, const int* __restrict__ alen, float* __restrict__ out) {
  int qt = blockIdx.x, h = blockIdx.y, b = blockIdx.z;
  int g = h >> 2;
  int len = alen[b];
  int q0 = qt * 64;
  if (q0 + 64 <= len) return;                 // no invalid rows here
  int nskip = max(len - q0, 0);
  __shared__ __align__(16) char smem[44288];
  ushort_t* Qt = (ushort_t*)smem;             // [64][72] (d, qi)
  ushort_t* Kt = (ushort_t*)(smem + 9216);    // [64][72] (d, kj)
  ushort_t* Vt = (ushort_t*)(smem + 18432);   // [64][72] (kj, d)
  float* Sq = (float*)(smem + 27648);         // [64][65]
  int t = threadIdx.x;
  int tx = t & 15, ty = t >> 4;
#pragma unroll
  for (int p = 0; p < 4; ++p) {
    int qi = p * 16 + ty;
    const float4 v4 = *(const float4*)&q[((long)(b * Tc + q0 + qi)) * Dc + h * 64 + tx * 4];
    Qt[(tx * 4 + 0) * 72 + qi] = f2us(v4.x);
    Qt[(tx * 4 + 1) * 72 + qi] = f2us(v4.y);
    Qt[(tx * 4 + 2) * 72 + qi] = f2us(v4.z);
    Qt[(tx * 4 + 3) * 72 + qi] = f2us(v4.w);
  }
  int qi0 = ty * 4, kj0 = tx * 4, d0 = tx * 4;
  float m[4] = {NEGB, NEGB, NEGB, NEGB};
  float l[4] = {0.f, 0.f, 0.f, 0.f};
  float acc[4][4] = {};
  const ushort_t* Rqu = (const ushort_t*)Rq;
  long rqbase = ((long)(b * 8 + h) * Tc + q0 + qi0) * 384;
  for (int kt = 0; kt < 18; ++kt) {
    __syncthreads();                          // prev PV reads done
#pragma unroll
    for (int p = 0; p < 4; ++p) {
      int kj = p * 16 + ty;
      int ko = kt * 64 - 128 + kj;
      float4 kv = make_float4(0.f, 0.f, 0.f, 0.f), vv = kv;
      if (ko >= 0) {
        long base = ((long)(b * Tc + ko)) * 128 + g * 64 + tx * 4;
        kv = *(const float4*)&kb[base];
        vv = *(const float4*)&vb[base];
      }
      Kt[(tx * 4 + 0) * 72 + kj] = f2us(kv.x);
      Kt[(tx * 4 + 1) * 72 + kj] = f2us(kv.y);
      Kt[(tx * 4 + 2) * 72 + kj] = f2us(kv.z);
      Kt[(tx * 4 + 3) * 72 + kj] = f2us(kv.w);
      uint2 P;
      P.x = (uint_t)f2us(vv.x) | ((uint_t)f2us(vv.y) << 16);
      P.y = (uint_t)f2us(vv.z) | ((uint_t)f2us(vv.w) << 16);
      *(uint2*)&Vt[kj * 72 + tx * 4] = P;
    }
    __syncthreads();
    float s[4][4];
#pragma unroll
    for (int i = 0; i < 4; ++i)
#pragma unroll
      for (int j = 0; j < 4; ++j) s[i][j] = 0.f;
    for (int d = 0; d < 64; ++d) {
      uint2 qw = *(const uint2*)&Qt[d * 72 + qi0];
      uint2 kw = *(const uint2*)&Kt[d * 72 + kj0];
      float qv[4] = {lo16(qw.x), hi16(qw.x), lo16(qw.y), hi16(qw.y)};
      float kv[4] = {lo16(kw.x), hi16(kw.x), lo16(kw.y), hi16(kw.y)};
#pragma unroll
      for (int i = 0; i < 4; ++i)
#pragma unroll
        for (int j = 0; j < 4; ++j) s[i][j] += qv[i] * kv[j];
    }
    int dbase = 64 * (qt - kt) + 128;
#pragma unroll
    for (int i = 0; i < 4; ++i) {
#pragma unroll
      for (int j = 0; j < 4; ++j) {
        int dist = dbase + (qi0 + i) - (kj0 + j);
        dist = min(max(dist, -(MPc - 1)), MPc - 1);
        s[i][j] += us2f(Rqu[rqbase + (long)i * 384 + dist + 191]);
      }
    }
    float alpha[4];
#pragma unroll
    for (int i = 0; i < 4; ++i) {
      float tm = s[i][0];
#pragma unroll
      for (int j = 1; j < 4; ++j) tm = fmaxf(tm, s[i][j]);
      for (int o = 1; o < 16; o <<= 1) tm = fmaxf(tm, __shfl_xor(tm, o, 64));
      float mn = fmaxf(m[i], tm);
      alpha[i] = __expf(m[i] - mn);
      float ps = 0.f;
#pragma unroll
      for (int j = 0; j < 4; ++j) { s[i][j] = __expf(s[i][j] - mn); ps += s[i][j]; }
      for (int o = 1; o < 16; o <<= 1) ps += __shfl_xor(ps, o, 64);
      l[i] = l[i] * alpha[i] + ps;
      m[i] = mn;
    }
#pragma unroll
    for (int i = 0; i < 4; ++i)
#pragma unroll
      for (int j = 0; j < 4; ++j) Sq[(qi0 + i) * 65 + kj0 + j] = s[i][j];
    __syncthreads();
#pragma unroll
    for (int i = 0; i < 4; ++i)
#pragma unroll
      for (int j = 0; j < 4; ++j) acc[i][j] *= alpha[i];
    for (int kj = 0; kj < 64; ++kj) {
      uint2 vw = *(const uint2*)&Vt[kj * 72 + d0];
      float v0 = lo16(vw.x), v1 = hi16(vw.x), v2 = lo16(vw.y), v3 = hi16(vw.y);
#pragma unroll
      for (int i = 0; i < 4; ++i) {
        float p = Sq[(qi0 + i) * 65 + kj];
        acc[i][0] += p * v0; acc[i][1] += p * v1; acc[i][2] += p * v2; acc[i][3] += p * v3;
      }
    }
  }
#pragma unroll
  for (int i = 0; i < 4; ++i) {
    int qi = qi0 + i;
    if (qi >= nskip) {
      float inv = 1.0f / l[i];
      float4 o4 = make_float4(acc[i][0] * inv, acc[i][1] * inv, acc[i][2] * inv, acc[i][3] * inv);
      *(float4*)&out[((long)(b * Tc + q0 + qi)) * Dc + h * 64 + d0] = o4;
    }
  }
}

// ---------------- Fallback attention (old, correct, slow) ----------------
__global__ __launch_bounds__(256) void k_attn(const float* __restrict__ q,
    const float* __restrict__ kbuf, const float* __restrict__ vbuf,
    const void* __restrict__ rel, long roff, const int* __restrict__ alen,
    float* __restrict__ out, const int* __restrict__ flag) {
  int f32 = flag[0];
  int qo = blockIdx.x, h = blockIdx.y, b = blockIdx.z;
  int g = h >> 2;
  int len = alen[b];
  int tid = threadIdx.x;
  __shared__ float qs[HDc];
  __shared__ float sc[Tc + LCc];
  __shared__ float red[256];
  __shared__ float pacc[4][HDc];
  if (tid < HDc) qs[tid] = q[(long)(b * Tc + qo) * Dc + h * HDc + tid];
  __syncthreads();
  bool vq = qo < len;
  int lo, hi;
  if (vq) { int c = (qo >> 6) << 6; lo = c - LCc; hi = c + 64; }
  else    { lo = -LCc; hi = Tc; }
  int nk = hi - lo;
  for (int idx = tid; idx < nk; idx += 256) {
    int ko = lo + idx;
    float s;
    if (vq && ko >= len) {
      s = NEGB;
    } else {
      s = 0.0f;
      if (ko >= 0) {
        const float* kr = kbuf + (long)(b * Tc + ko) * 128 + g * HDc;
#pragma unroll
        for (int d = 0; d < HDc; ++d) s += qs[d] * kr[d];
      }
      int dist = qo - ko;
      if (dist > MPc - 1) dist = MPc - 1;
      if (dist < -(MPc - 1)) dist = -(MPc - 1);
      long rb = roff + (long)(dist + MPc - 1) * HDc;
#pragma unroll
      for (int d = 0; d < HDc; ++d) s += qs[d] * wload(rel, rb + d, f32);
    }
    sc[idx] = s;
  }
  __syncthreads();
  float lm = NEGB;
  for (int idx = tid; idx < nk; idx += 256) lm = fmaxf(lm, sc[idx]);
  red[tid] = lm;
  __syncthreads();
  for (int off = 128; off > 0; off >>= 1) { if (tid < off) red[tid] = fmaxf(red[tid], red[tid + off]); __syncthreads(); }
  float mx = red[0];
  __syncthreads();
  float ls = 0.0f;
  for (int idx = tid; idx < nk; idx += 256) { float p = __expf(sc[idx] - mx); sc[idx] = p; ls += p; }
  red[tid] = ls;
  __syncthreads();
  for (int off = 128; off > 0; off >>= 1) { if (tid < off) red[tid] += red[tid + off]; __syncthreads(); }
  float denom = red[0];
  __syncthreads();
  int d = tid & 63, part = tid >> 6;
  float acc = 0.0f;
  for (int idx = part; idx < nk; idx += 4) {
    int ko = lo + idx;
    if (ko >= 0) acc += sc[idx] * vbuf[(long)(b * Tc + ko) * 128 + g * HDc + d];
  }
  pacc[part][d] = acc;
  __syncthreads();
  if (tid < HDc) {
    float o = (pacc[0][tid] + pacc[1][tid] + pacc[2][tid] + pacc[3][tid]) / denom;
    out[(long)(b * Tc + qo) * Dc + h * HDc + tid] = o;
  }
}

// ---------------- elementwise ----------------
__global__ void k_glu_conv(float* __restrict__ h, int n) {
  int i = blockIdx.x * 256 + threadIdx.x;
  if (i >= n) return;
  int r = i >> 9, j = i & 511;
  float a = h[(long)r * 1024 + j], g = h[(long)r * 1024 + 512 + j];
  h[(long)r * 1024 + j] = a * (1.0f / (1.0f + __expf(-g)));
}
__global__ void k_swiglu(float* __restrict__ h, int n) {
  int i = blockIdx.x * 256 + threadIdx.x;
  if (i >= n) return;
  int r = i >> 10, j = i & 1023;
  float a = h[(long)r * 2048 + j], bb = h[(long)r * 2048 + 1024 + j];
  h[(long)r * 2048 + j] = (a / (1.0f + __expf(-a))) * bb;
}
__global__ void k_dwconv(const float* __restrict__ in, const void* __restrict__ dw, long doff,
                         float* __restrict__ out, int n, const int* __restrict__ flag) {
  int f32 = flag[0];
  int i = blockIdx.x * 256 + threadIdx.x;
  if (i >= n) return;
  int d = i & 511;
  int t = (i >> 9) & (Tc - 1);
  int b = i >> 19;
  float acc = 0.0f;
#pragma unroll
  for (int j = 0; j < 9; ++j) {
    int tt = t + j - 4;
    if (tt >= 0 && tt < Tc) acc += in[((long)(b * Tc + tt) << 10) + d] * wload(dw, doff + d * 9 + j, f32);
  }
  out[i] = acc * (1.0f / (1.0f + __expf(-acc)));
}

extern "C" void kernel_launch(void* const* d_in, const int* in_sizes, int n_in,
                              void* d_out, int out_size, void* d_ws, size_t ws_size,
                              hipStream_t stream) {
  const void* x_in = d_in[0];
  const int*  alen = (const int*)d_in[1];
  const void* ln1w = d_in[2];
  const void* ln1b = d_in[3];
  const void* wq   = d_in[4];
  const void* wk   = d_in[5];
  const void* wv   = d_in[6];
  const void* wo   = d_in[7];
  const void* rel  = d_in[8];
  const void* ln2w = d_in[9];
  const void* ln2b = d_in[10];
  const void* pw1  = d_in[11];
  const void* dwv  = d_in[12];
  const void* pw2  = d_in[13];
  const void* ln3w = d_in[14];
  const void* ln3b = d_in[15];
  const void* w1   = d_in[16];
  const void* w2   = d_in[17];

  int*   flag = (int*)d_ws;
  float* xf  = (float*)((char*)d_ws + 256);   // 2M floats: residual stream (also qb)
  float* lnb = xf + NE;                       // 2M floats
  float* big = lnb + NE;                      // 8M floats
  float* qb = xf;                             // q overlays xf (xf dead after k_ln)
  float* kb = big;                            // 0.5M
  float* vb = big + (long)NBT * 128;          // 0.5M
  float* ab = big + (long)NBT * 256;          // 2M
  float* cb = big + (long)NBT * 1024;         // 2M (conv phase)
  bf16* Rqbuf = (bf16*)((char*)d_ws + 256 + NE * 3 * 4 + (long)NBT * 2048 * 4);
  bool rq_ok = ws_size >= (size_t)(256 + NE * 3 * 4 + (long)NBT * 2048 * 4 + (long)32 * Tc * 384 * 2);

  k_detect<<<1, 256, 0, stream>>>(x_in, flag);
  k_in<<<(int)((NE + 255) / 256), 256, 0, stream>>>(x_in, xf, (int)NE, flag);

  for (int i = 0; i < 4; ++i) {
    long oQ = (long)i * Dc * Dc;
    long oKV = (long)i * 128 * Dc;
    long oR = (long)i * (2 * MPc - 1) * HDc;
    long oP1 = (long)i * 1024 * Dc;
    long oDW = (long)i * Dc * 9;
    long oF1 = (long)i * 2048 * Dc;
    long oF2 = (long)i * Dc * 1024;
    long oLN = (long)i * Dc;

    // ---- attention ----
    k_ln<<<NBT, 256, 0, stream>>>(xf, ln1w, ln1b, oLN, lnb, flag);
    k_gemm<<<dim3(8, 64), 256, 0, stream>>>(lnb, Dc, wq, oQ, qb, Dc, nullptr, 0.125f, NBT, Dc, Dc, flag);
    k_gemm<<<dim3(2, 64), 256, 0, stream>>>(lnb, Dc, wk, oKV, kb, 128, nullptr, 1.0f, NBT, 128, Dc, flag);
    k_gemm<<<dim3(2, 64), 256, 0, stream>>>(lnb, Dc, wv, oKV, vb, 128, nullptr, 1.0f, NBT, 128, Dc, flag);
    if (rq_ok) {
      k_rq<<<dim3(6, 16, 32), 256, 0, stream>>>(qb, rel, oR, Rqbuf, flag);
      k_attn_chunk<<<dim3(16, 8, 4), 256, 0, stream>>>(qb, kb, vb, Rqbuf, alen, ab);
      k_attn_inv<<<dim3(16, 8, 4), 256, 0, stream>>>(qb, kb, vb, Rqbuf, alen, ab);
    } else {
      k_attn<<<dim3(Tc, Hc, Bc), 256, 0, stream>>>(qb, kb, vb, rel, oR, alen, ab, flag);
    }
    k_gemm<<<dim3(8, 64), 256, 0, stream>>>(ab, Dc, wo, oQ, xf, Dc, lnb, 1.0f, NBT, Dc, Dc, flag);

    // ---- conv ----
    k_ln<<<NBT, 256, 0, stream>>>(xf, ln2w, ln2b, oLN, lnb, flag);
    k_gemm<<<dim3(16, 64), 256, 0, stream>>>(lnb, Dc, pw1, oP1, big, 1024, nullptr, 1.0f, NBT, 1024, Dc, flag);
    k_glu_conv<<<NBT * 512 / 256, 256, 0, stream>>>(big, NBT * 512);
    k_dwconv<<<NBT * 512 / 256, 256, 0, stream>>>(big, dwv, oDW, cb, NBT * 512, flag);
    k_gemm<<<dim3(8, 64), 256, 0, stream>>>(cb, 512, pw2, oQ, xf, Dc, lnb, 1.0f, NBT, Dc, Dc, flag);

    // ---- ffn ----
    k_ln<<<NBT, 256, 0, stream>>>(xf, ln3w, ln3b, oLN, lnb, flag);
    k_gemm<<<dim3(32, 64), 256, 0, stream>>>(lnb, Dc, w1, oF1, big, 2048, nullptr, 1.0f, NBT, 2048, Dc, flag);
    k_swiglu<<<NBT * 1024 / 256, 256, 0, stream>>>(big, NBT * 1024);
    k_gemm<<<dim3(8, 64), 256, 0, stream>>>(big, 2048, w2, oF2, xf, Dc, lnb, 1.0f, NBT, Dc, 1024, flag);
  }

  k_out<<<(int)((NE + 255) / 256), 256, 0, stream>>>(xf, d_out, (int)NE, flag);
}

// Round 5
// 2510.672 us; speedup vs baseline: 4.2816x; 1.5589x over previous
//
#include <hip/hip_runtime.h>
#include <hip/hip_bf16.h>

typedef __hip_bfloat16 bf16;
typedef unsigned short ushort_t;
typedef unsigned int uint_t;
typedef __attribute__((ext_vector_type(8))) short short8;
typedef __attribute__((ext_vector_type(4))) float floatx4;

__device__ __forceinline__ float b2f(bf16 x) { return __bfloat162float(x); }
__device__ __forceinline__ ushort_t f2us(float f) { bf16 h = __float2bfloat16(f); return *(ushort_t*)&h; }
__device__ __forceinline__ float us2f(ushort_t u) { return __uint_as_float(((uint_t)u) << 16); }
__device__ __forceinline__ float lo16(uint_t u) { return __uint_as_float(u << 16); }
__device__ __forceinline__ float hi16(uint_t u) { return __uint_as_float(u & 0xFFFF0000u); }

constexpr int Bc = 4, Tc = 1024, Dc = 512, Hc = 8, HDc = 64;
constexpr int LCc = 128, MPc = 192;
constexpr float EPSc = 1e-4f;
constexpr int NBT = Bc * Tc;
constexpr long NE = (long)NBT * Dc;
constexpr float NEGB = -1e30f;

__device__ __forceinline__ float wload(const void* p, long i, int f32) {
  return f32 ? ((const float*)p)[i] : b2f(((const bf16*)p)[i]);
}

// ---------------- dtype detector ----------------
__global__ void k_detect(const void* __restrict__ x, int* __restrict__ flag) {
  __shared__ int s[256];
  int t = threadIdx.x;
  const unsigned short* u = (const unsigned short*)x;
  int bad = 0;
  for (int j = t; j < 2048; j += 256) {
    int e = (u[j] >> 7) & 0xFF;
    if (e == 0xFF || e > 0x8F || (e != 0 && e < 0x6F)) bad++;
  }
  s[t] = bad;
  __syncthreads();
  for (int off = 128; off > 0; off >>= 1) { if (t < off) s[t] += s[t + off]; __syncthreads(); }
  if (t == 0) flag[0] = (s[0] > 16) ? 1 : 0;
}

__global__ void k_in(const void* __restrict__ in, float* __restrict__ out, int n,
                     const int* __restrict__ flag) {
  int i = blockIdx.x * 256 + threadIdx.x;
  if (i < n) out[i] = wload(in, i, flag[0]);
}
__global__ void k_out(const float* __restrict__ in, void* __restrict__ out, int n,
                      const int* __restrict__ flag) {
  int i = blockIdx.x * 256 + threadIdx.x;
  if (i >= n) return;
  if (flag[0]) ((float*)out)[i] = in[i];
  else         ((bf16*)out)[i] = __float2bfloat16(in[i]);
}

// ---------------- LayerNorm ----------------
__global__ __launch_bounds__(256) void k_ln(const float* __restrict__ x,
    const void* __restrict__ w, const void* __restrict__ bb, long woff,
    float* __restrict__ o, const int* __restrict__ flag) {
  int f32 = flag[0];
  int row = blockIdx.x;
  int t = threadIdx.x;
  const float* xr = x + (long)row * Dc;
  float x0 = xr[t], x1 = xr[t + 256];
  __shared__ float red[256];
  red[t] = x0 + x1;
  __syncthreads();
  for (int off = 128; off > 0; off >>= 1) { if (t < off) red[t] += red[t + off]; __syncthreads(); }
  float mean = red[0] * (1.0f / Dc);
  __syncthreads();
  float d0 = x0 - mean, d1 = x1 - mean;
  red[t] = d0 * d0 + d1 * d1;
  __syncthreads();
  for (int off = 128; off > 0; off >>= 1) { if (t < off) red[t] += red[t + off]; __syncthreads(); }
  float inv = 1.0f / sqrtf(red[0] * (1.0f / Dc) + EPSc);
  float* orow = o + (long)row * Dc;
  orow[t]       = d0 * inv * wload(w, woff + t, f32)       + wload(bb, woff + t, f32);
  orow[t + 256] = d1 * inv * wload(w, woff + t + 256, f32) + wload(bb, woff + t + 256, f32);
}

// ---------------- MFMA GEMM: C[M,N] = alpha * A[M,K](f32) @ W[N,K]^T (+addend) ----------------
// 128x128 tile, BK=32, 256 threads = 4 waves (2x2 of 64x64), mfma 16x16x32 bf16.
// LDS row stride 40 bf16 (80 B): 16B-aligned rows, <=2-way bank aliasing.
__global__ __launch_bounds__(256) void k_gemm_m(const float* __restrict__ A, int lda,
    const void* __restrict__ W, long woff, float* __restrict__ C, int ldc,
    const float* __restrict__ addend, float alpha, int N, int K,
    const int* __restrict__ flag) {
  int f32 = flag[0];
  __shared__ ushort_t As[128 * 40];
  __shared__ ushort_t Ws[128 * 40];
  int tid = threadIdx.x;
  int m0 = blockIdx.y * 128, n0 = blockIdx.x * 128;
  int r = tid >> 1, hc = (tid & 1) * 16;
  int lane = tid & 63, wv = tid >> 6;
  int wm = (wv >> 1) * 64, wn = (wv & 1) * 64;
  int l15 = lane & 15, quad = lane >> 4;
  floatx4 acc[4][4];
#pragma unroll
  for (int i = 0; i < 4; ++i)
#pragma unroll
    for (int j = 0; j < 4; ++j) acc[i][j] = 0;
  for (int k0 = 0; k0 < K; k0 += 32) {
    {
      const float* Ap = A + (long)(m0 + r) * lda + k0 + hc;
      ushort_t tmp[16];
#pragma unroll
      for (int u = 0; u < 4; ++u) {
        float4 v = *(const float4*)(Ap + u * 4);
        tmp[u * 4 + 0] = f2us(v.x); tmp[u * 4 + 1] = f2us(v.y);
        tmp[u * 4 + 2] = f2us(v.z); tmp[u * 4 + 3] = f2us(v.w);
      }
      *(uint4*)&As[r * 40 + hc] = *(uint4*)&tmp[0];
      *(uint4*)&As[r * 40 + hc + 8] = *(uint4*)&tmp[8];
    }
    {
      long wb = woff + (long)(n0 + r) * K + k0 + hc;
      if (f32) {
        const float* Wp = (const float*)W + wb;
        ushort_t tmp[16];
#pragma unroll
        for (int u = 0; u < 4; ++u) {
          float4 v = *(const float4*)(Wp + u * 4);
          tmp[u * 4 + 0] = f2us(v.x); tmp[u * 4 + 1] = f2us(v.y);
          tmp[u * 4 + 2] = f2us(v.z); tmp[u * 4 + 3] = f2us(v.w);
        }
        *(uint4*)&Ws[r * 40 + hc] = *(uint4*)&tmp[0];
        *(uint4*)&Ws[r * 40 + hc + 8] = *(uint4*)&tmp[8];
      } else {
        const ushort_t* Wp = (const ushort_t*)W + wb;
        *(uint4*)&Ws[r * 40 + hc] = *(const uint4*)(Wp);
        *(uint4*)&Ws[r * 40 + hc + 8] = *(const uint4*)(Wp + 8);
      }
    }
    __syncthreads();
    short8 af[4], bfr[4];
#pragma unroll
    for (int i = 0; i < 4; ++i) af[i] = *(short8*)&As[(wm + i * 16 + l15) * 40 + quad * 8];
#pragma unroll
    for (int j = 0; j < 4; ++j) bfr[j] = *(short8*)&Ws[(wn + j * 16 + l15) * 40 + quad * 8];
#pragma unroll
    for (int i = 0; i < 4; ++i)
#pragma unroll
      for (int j = 0; j < 4; ++j)
        acc[i][j] = __builtin_amdgcn_mfma_f32_16x16x32_bf16(af[i], bfr[j], acc[i][j], 0, 0, 0);
    __syncthreads();
  }
#pragma unroll
  for (int i = 0; i < 4; ++i) {
#pragma unroll
    for (int j = 0; j < 4; ++j) {
#pragma unroll
      for (int rg = 0; rg < 4; ++rg) {
        int m = m0 + wm + i * 16 + quad * 4 + rg;
        int n = n0 + wn + j * 16 + l15;
        float v = alpha * acc[i][j][rg];
        if (addend) v += addend[(long)m * ldc + n];
        C[(long)m * ldc + n] = v;
      }
    }
  }
}

// ---------------- MFMA Rq: Rq[(bh*1024+qo)][ri] = q . rel[min(ri,382)], bf16 out ----------------
__global__ __launch_bounds__(256) void k_rq_m(const float* __restrict__ qb,
    const void* __restrict__ rel, long roff, bf16* __restrict__ Rq,
    const int* __restrict__ flag) {
  int f32 = flag[0];
  __shared__ ushort_t As[128 * 40];
  __shared__ ushort_t Ws[128 * 40];
  int tid = threadIdx.x;
  int bh = blockIdx.z;
  const float* A = qb + (long)(bh >> 3) * Tc * Dc + (bh & 7) * 64;
  int m0 = blockIdx.y * 128, n0 = blockIdx.x * 128;
  int r = tid >> 1, hc = (tid & 1) * 16;
  int lane = tid & 63, wv = tid >> 6;
  int wm = (wv >> 1) * 64, wn = (wv & 1) * 64;
  int l15 = lane & 15, quad = lane >> 4;
  floatx4 acc[4][4];
#pragma unroll
  for (int i = 0; i < 4; ++i)
#pragma unroll
    for (int j = 0; j < 4; ++j) acc[i][j] = 0;
  for (int k0 = 0; k0 < 64; k0 += 32) {
    {
      const float* Ap = A + (long)(m0 + r) * Dc + k0 + hc;
      ushort_t tmp[16];
#pragma unroll
      for (int u = 0; u < 4; ++u) {
        float4 v = *(const float4*)(Ap + u * 4);
        tmp[u * 4 + 0] = f2us(v.x); tmp[u * 4 + 1] = f2us(v.y);
        tmp[u * 4 + 2] = f2us(v.z); tmp[u * 4 + 3] = f2us(v.w);
      }
      *(uint4*)&As[r * 40 + hc] = *(uint4*)&tmp[0];
      *(uint4*)&As[r * 40 + hc + 8] = *(uint4*)&tmp[8];
    }
    {
      int wr = n0 + r; if (wr > 382) wr = 382;
      long wb = roff + (long)wr * 64 + k0 + hc;
      if (f32) {
        const float* Wp = (const float*)rel + wb;
        ushort_t tmp[16];
#pragma unroll
        for (int u = 0; u < 4; ++u) {
          float4 v = *(const float4*)(Wp + u * 4);
          tmp[u * 4 + 0] = f2us(v.x); tmp[u * 4 + 1] = f2us(v.y);
          tmp[u * 4 + 2] = f2us(v.z); tmp[u * 4 + 3] = f2us(v.w);
        }
        *(uint4*)&Ws[r * 40 + hc] = *(uint4*)&tmp[0];
        *(uint4*)&Ws[r * 40 + hc + 8] = *(uint4*)&tmp[8];
      } else {
        const ushort_t* Wp = (const ushort_t*)rel + wb;
        *(uint4*)&Ws[r * 40 + hc] = *(const uint4*)(Wp);
        *(uint4*)&Ws[r * 40 + hc + 8] = *(const uint4*)(Wp + 8);
      }
    }
    __syncthreads();
    short8 af[4], bfr[4];
#pragma unroll
    for (int i = 0; i < 4; ++i) af[i] = *(short8*)&As[(wm + i * 16 + l15) * 40 + quad * 8];
#pragma unroll
    for (int j = 0; j < 4; ++j) bfr[j] = *(short8*)&Ws[(wn + j * 16 + l15) * 40 + quad * 8];
#pragma unroll
    for (int i = 0; i < 4; ++i)
#pragma unroll
      for (int j = 0; j < 4; ++j)
        acc[i][j] = __builtin_amdgcn_mfma_f32_16x16x32_bf16(af[i], bfr[j], acc[i][j], 0, 0, 0);
    __syncthreads();
  }
#pragma unroll
  for (int i = 0; i < 4; ++i) {
#pragma unroll
    for (int j = 0; j < 4; ++j) {
      int n = n0 + wn + j * 16 + l15;
      if (n >= 384) continue;
#pragma unroll
      for (int rg = 0; rg < 4; ++rg) {
        int m = m0 + wm + i * 16 + quad * 4 + rg;
        Rq[((long)bh * Tc + m) * 384 + n] = __float2bfloat16(acc[i][j][rg]);
      }
    }
  }
}

// ---------------- Chunked attention (valid rows) ----------------
__global__ __launch_bounds__(256) void k_attn_chunk(const float* __restrict__ q,
    const float* __restrict__ kb, const float* __restrict__ vb,
    const bf16* __restrict__ Rq, const int* __restrict__ alen, float* __restrict__ out) {
  int c = blockIdx.x, h = blockIdx.y, b = blockIdx.z;
  int g = h >> 2;
  int len = alen[b];
  int q0 = c * 64;
  if (q0 >= len) return;
  int nvalid = min(len - q0, 64);
  int lo = q0 - 128;
  __shared__ __align__(16) char smem[62464];
  ushort_t* Qt = (ushort_t*)smem;                 // [64][72] (d, qi)
  ushort_t* Kt = (ushort_t*)(smem + 9216);        // [64][200] (d, kj)
  ushort_t* Vs = (ushort_t*)(smem + 34816);       // [192][72] (kj, d)
  ushort_t* Sqt = (ushort_t*)smem;                // [192][72] (kj, qi) overlay
  int t = threadIdx.x;
  int tx = t & 15, ty = t >> 4;
#pragma unroll
  for (int p = 0; p < 4; ++p) {
    int qi = p * 16 + ty;
    const float4 v4 = *(const float4*)&q[((long)(b * Tc + q0 + qi)) * Dc + h * 64 + tx * 4];
    Qt[(tx * 4 + 0) * 72 + qi] = f2us(v4.x);
    Qt[(tx * 4 + 1) * 72 + qi] = f2us(v4.y);
    Qt[(tx * 4 + 2) * 72 + qi] = f2us(v4.z);
    Qt[(tx * 4 + 3) * 72 + qi] = f2us(v4.w);
  }
#pragma unroll
  for (int p = 0; p < 12; ++p) {
    int kj = p * 16 + ty;
    int ko = lo + kj;
    float4 kv = make_float4(0.f, 0.f, 0.f, 0.f), vv = kv;
    if (ko >= 0) {
      long base = ((long)(b * Tc + ko)) * 128 + g * 64 + tx * 4;
      kv = *(const float4*)&kb[base];
      vv = *(const float4*)&vb[base];
    }
    Kt[(tx * 4 + 0) * 200 + kj] = f2us(kv.x);
    Kt[(tx * 4 + 1) * 200 + kj] = f2us(kv.y);
    Kt[(tx * 4 + 2) * 200 + kj] = f2us(kv.z);
    Kt[(tx * 4 + 3) * 200 + kj] = f2us(kv.w);
    uint2 P;
    P.x = (uint_t)f2us(vv.x) | ((uint_t)f2us(vv.y) << 16);
    P.y = (uint_t)f2us(vv.z) | ((uint_t)f2us(vv.w) << 16);
    *(uint2*)&Vs[kj * 72 + tx * 4] = P;
  }
  __syncthreads();
  int qi0 = ty * 4, kj0 = tx * 12;
  float s[4][12];
#pragma unroll
  for (int i = 0; i < 4; ++i)
#pragma unroll
    for (int j = 0; j < 12; ++j) s[i][j] = 0.f;
  for (int d = 0; d < 64; ++d) {
    uint2 qw = *(const uint2*)&Qt[d * 72 + qi0];
    float qv[4] = {lo16(qw.x), hi16(qw.x), lo16(qw.y), hi16(qw.y)};
    uint2 k0w = *(const uint2*)&Kt[d * 200 + kj0];
    uint2 k1w = *(const uint2*)&Kt[d * 200 + kj0 + 4];
    uint2 k2w = *(const uint2*)&Kt[d * 200 + kj0 + 8];
    float kv[12] = {lo16(k0w.x), hi16(k0w.x), lo16(k0w.y), hi16(k0w.y),
                    lo16(k1w.x), hi16(k1w.x), lo16(k1w.y), hi16(k1w.y),
                    lo16(k2w.x), hi16(k2w.x), lo16(k2w.y), hi16(k2w.y)};
#pragma unroll
    for (int i = 0; i < 4; ++i)
#pragma unroll
      for (int j = 0; j < 12; ++j) s[i][j] += qv[i] * kv[j];
  }
  const ushort_t* Rqu = (const ushort_t*)Rq;
  long rqbase = ((long)(b * 8 + h) * Tc + q0 + qi0) * 384;
#pragma unroll
  for (int i = 0; i < 4; ++i) {
#pragma unroll
    for (int j = 0; j < 12; ++j) {
      int ri = (qi0 + i) - (kj0 + j) + 319;
      float rv = us2f(Rqu[rqbase + (long)i * 384 + ri]);
      int ko = lo + kj0 + j;
      s[i][j] = (ko >= len) ? NEGB : (s[i][j] + rv);
    }
  }
  float l[4];
#pragma unroll
  for (int i = 0; i < 4; ++i) {
    float mm = s[i][0];
#pragma unroll
    for (int j = 1; j < 12; ++j) mm = fmaxf(mm, s[i][j]);
    for (int o = 1; o < 16; o <<= 1) mm = fmaxf(mm, __shfl_xor(mm, o, 64));
    float ss = 0.f;
#pragma unroll
    for (int j = 0; j < 12; ++j) { s[i][j] = __expf(s[i][j] - mm); ss += s[i][j]; }
    for (int o = 1; o < 16; o <<= 1) ss += __shfl_xor(ss, o, 64);
    l[i] = ss;
  }
  __syncthreads();
#pragma unroll
  for (int i = 0; i < 4; ++i)
#pragma unroll
    for (int j = 0; j < 12; ++j) Sqt[(kj0 + j) * 72 + qi0 + i] = f2us(s[i][j]);
  __syncthreads();
  int d0 = tx * 4;
  float acc[4][4] = {};
  for (int kj = 0; kj < 192; ++kj) {
    uint2 vw = *(const uint2*)&Vs[kj * 72 + d0];
    uint2 pw = *(const uint2*)&Sqt[kj * 72 + qi0];
    float v0 = lo16(vw.x), v1 = hi16(vw.x), v2 = lo16(vw.y), v3 = hi16(vw.y);
    float p0 = lo16(pw.x), p1 = hi16(pw.x), p2 = lo16(pw.y), p3 = hi16(pw.y);
    acc[0][0] += p0 * v0; acc[0][1] += p0 * v1; acc[0][2] += p0 * v2; acc[0][3] += p0 * v3;
    acc[1][0] += p1 * v0; acc[1][1] += p1 * v1; acc[1][2] += p1 * v2; acc[1][3] += p1 * v3;
    acc[2][0] += p2 * v0; acc[2][1] += p2 * v1; acc[2][2] += p2 * v2; acc[2][3] += p2 * v3;
    acc[3][0] += p3 * v0; acc[3][1] += p3 * v1; acc[3][2] += p3 * v2; acc[3][3] += p3 * v3;
  }
#pragma unroll
  for (int i = 0; i < 4; ++i) {
    int qi = qi0 + i;
    if (qi < nvalid) {
      float inv = 1.0f / l[i];
      float4 o4 = make_float4(acc[i][0] * inv, acc[i][1] * inv, acc[i][2] * inv, acc[i][3] * inv);
      *(float4*)&out[((long)(b * Tc + q0 + qi)) * Dc + h * 64 + d0] = o4;
    }
  }
}

// ---------------- Invalid-row attention ----------------
__global__ __launch_bounds__(256) void k_attn_inv(const float* __restrict__ q,
    const float* __restrict__ kb, const float* __restrict__ vb,
    const bf16* __restrict__ Rq, const int* __restrict__ alen, float* __restrict__ out) {
  int qt = blockIdx.x, h = blockIdx.y, b = blockIdx.z;
  int g = h >> 2;
  int len = alen[b];
  int q0 = qt * 64;
  if (q0 + 64 <= len) return;
  int nskip = max(len - q0, 0);
  __shared__ __align__(16) char smem[44288];
  ushort_t* Qt = (ushort_t*)smem;
  ushort_t* Kt = (ushort_t*)(smem + 9216);
  ushort_t* Vt = (ushort_t*)(smem + 18432);
  float* Sq = (float*)(smem + 27648);
  int t = threadIdx.x;
  int tx = t & 15, ty = t >> 4;
#pragma unroll
  for (int p = 0; p < 4; ++p) {
    int qi = p * 16 + ty;
    const float4 v4 = *(const float4*)&q[((long)(b * Tc + q0 + qi)) * Dc + h * 64 + tx * 4];
    Qt[(tx * 4 + 0) * 72 + qi] = f2us(v4.x);
    Qt[(tx * 4 + 1) * 72 + qi] = f2us(v4.y);
    Qt[(tx * 4 + 2) * 72 + qi] = f2us(v4.z);
    Qt[(tx * 4 + 3) * 72 + qi] = f2us(v4.w);
  }
  int qi0 = ty * 4, kj0 = tx * 4, d0 = tx * 4;
  float m[4] = {NEGB, NEGB, NEGB, NEGB};
  float l[4] = {0.f, 0.f, 0.f, 0.f};
  float acc[4][4] = {};
  const ushort_t* Rqu = (const ushort_t*)Rq;
  long rqbase = ((long)(b * 8 + h) * Tc + q0 + qi0) * 384;
  for (int kt = 0; kt < 18; ++kt) {
    __syncthreads();
#pragma unroll
    for (int p = 0; p < 4; ++p) {
      int kj = p * 16 + ty;
      int ko = kt * 64 - 128 + kj;
      float4 kv = make_float4(0.f, 0.f, 0.f, 0.f), vv = kv;
      if (ko >= 0) {
        long base = ((long)(b * Tc + ko)) * 128 + g * 64 + tx * 4;
        kv = *(const float4*)&kb[base];
        vv = *(const float4*)&vb[base];
      }
      Kt[(tx * 4 + 0) * 72 + kj] = f2us(kv.x);
      Kt[(tx * 4 + 1) * 72 + kj] = f2us(kv.y);
      Kt[(tx * 4 + 2) * 72 + kj] = f2us(kv.z);
      Kt[(tx * 4 + 3) * 72 + kj] = f2us(kv.w);
      uint2 P;
      P.x = (uint_t)f2us(vv.x) | ((uint_t)f2us(vv.y) << 16);
      P.y = (uint_t)f2us(vv.z) | ((uint_t)f2us(vv.w) << 16);
      *(uint2*)&Vt[kj * 72 + tx * 4] = P;
    }
    __syncthreads();
    float s[4][4];
#pragma unroll
    for (int i = 0; i < 4; ++i)
#pragma unroll
      for (int j = 0; j < 4; ++j) s[i][j] = 0.f;
    for (int d = 0; d < 64; ++d) {
      uint2 qw = *(const uint2*)&Qt[d * 72 + qi0];
      uint2 kw = *(const uint2*)&Kt[d * 72 + kj0];
      float qv[4] = {lo16(qw.x), hi16(qw.x), lo16(qw.y), hi16(qw.y)};
      float kv[4] = {lo16(kw.x), hi16(kw.x), lo16(kw.y), hi16(kw.y)};
#pragma unroll
      for (int i = 0; i < 4; ++i)
#pragma unroll
        for (int j = 0; j < 4; ++j) s[i][j] += qv[i] * kv[j];
    }
    int dbase = 64 * (qt - kt) + 128;
#pragma unroll
    for (int i = 0; i < 4; ++i) {
#pragma unroll
      for (int j = 0; j < 4; ++j) {
        int dist = dbase + (qi0 + i) - (kj0 + j);
        dist = min(max(dist, -(MPc - 1)), MPc - 1);
        s[i][j] += us2f(Rqu[rqbase + (long)i * 384 + dist + 191]);
      }
    }
    float alpha[4];
#pragma unroll
    for (int i = 0; i < 4; ++i) {
      float tm = s[i][0];
#pragma unroll
      for (int j = 1; j < 4; ++j) tm = fmaxf(tm, s[i][j]);
      for (int o = 1; o < 16; o <<= 1) tm = fmaxf(tm, __shfl_xor(tm, o, 64));
      float mn = fmaxf(m[i], tm);
      alpha[i] = __expf(m[i] - mn);
      float ps = 0.f;
#pragma unroll
      for (int j = 0; j < 4; ++j) { s[i][j] = __expf(s[i][j] - mn); ps += s[i][j]; }
      for (int o = 1; o < 16; o <<= 1) ps += __shfl_xor(ps, o, 64);
      l[i] = l[i] * alpha[i] + ps;
      m[i] = mn;
    }
#pragma unroll
    for (int i = 0; i < 4; ++i)
#pragma unroll
      for (int j = 0; j < 4; ++j) Sq[(qi0 + i) * 65 + kj0 + j] = s[i][j];
    __syncthreads();
#pragma unroll
    for (int i = 0; i < 4; ++i)
#pragma unroll
      for (int j = 0; j < 4; ++j) acc[i][j] *= alpha[i];
    for (int kj = 0; kj < 64; ++kj) {
      uint2 vw = *(const uint2*)&Vt[kj * 72 + d0];
      float v0 = lo16(vw.x), v1 = hi16(vw.x), v2 = lo16(vw.y), v3 = hi16(vw.y);
#pragma unroll
      for (int i = 0; i < 4; ++i) {
        float p = Sq[(qi0 + i) * 65 + kj];
        acc[i][0] += p * v0; acc[i][1] += p * v1; acc[i][2] += p * v2; acc[i][3] += p * v3;
      }
    }
  }
#pragma unroll
  for (int i = 0; i < 4; ++i) {
    int qi = qi0 + i;
    if (qi >= nskip) {
      float inv = 1.0f / l[i];
      float4 o4 = make_float4(acc[i][0] * inv, acc[i][1] * inv, acc[i][2] * inv, acc[i][3] * inv);
      *(float4*)&out[((long)(b * Tc + q0 + qi)) * Dc + h * 64 + d0] = o4;
    }
  }
}

// ---------------- Fallback attention ----------------
__global__ __launch_bounds__(256) void k_attn(const float* __restrict__ q,
    const float* __restrict__ kbuf, const float* __restrict__ vbuf,
    const void* __restrict__ rel, long roff, const int* __restrict__ alen,
    float* __restrict__ out, const int* __restrict__ flag) {
  int f32 = flag[0];
  int qo = blockIdx.x, h = blockIdx.y, b = blockIdx.z;
  int g = h >> 2;
  int len = alen[b];
  int tid = threadIdx.x;
  __shared__ float qs[HDc];
  __shared__ float sc[Tc + LCc];
  __shared__ float red[256];
  __shared__ float pacc[4][HDc];
  if (tid < HDc) qs[tid] = q[(long)(b * Tc + qo) * Dc + h * HDc + tid];
  __syncthreads();
  bool vq = qo < len;
  int lo, hi;
  if (vq) { int c = (qo >> 6) << 6; lo = c - LCc; hi = c + 64; }
  else    { lo = -LCc; hi = Tc; }
  int nk = hi - lo;
  for (int idx = tid; idx < nk; idx += 256) {
    int ko = lo + idx;
    float s;
    if (vq && ko >= len) {
      s = NEGB;
    } else {
      s = 0.0f;
      if (ko >= 0) {
        const float* kr = kbuf + (long)(b * Tc + ko) * 128 + g * HDc;
#pragma unroll
        for (int d = 0; d < HDc; ++d) s += qs[d] * kr[d];
      }
      int dist = qo - ko;
      if (dist > MPc - 1) dist = MPc - 1;
      if (dist < -(MPc - 1)) dist = -(MPc - 1);
      long rb = roff + (long)(dist + MPc - 1) * HDc;
#pragma unroll
      for (int d = 0; d < HDc; ++d) s += qs[d] * wload(rel, rb + d, f32);
    }
    sc[idx] = s;
  }
  __syncthreads();
  float lm = NEGB;
  for (int idx = tid; idx < nk; idx += 256) lm = fmaxf(lm, sc[idx]);
  red[tid] = lm;
  __syncthreads();
  for (int off = 128; off > 0; off >>= 1) { if (tid < off) red[tid] = fmaxf(red[tid], red[tid + off]); __syncthreads(); }
  float mx = red[0];
  __syncthreads();
  float ls = 0.0f;
  for (int idx = tid; idx < nk; idx += 256) { float p = __expf(sc[idx] - mx); sc[idx] = p; ls += p; }
  red[tid] = ls;
  __syncthreads();
  for (int off = 128; off > 0; off >>= 1) { if (tid < off) red[tid] += red[tid + off]; __syncthreads(); }
  float denom = red[0];
  __syncthreads();
  int d = tid & 63, part = tid >> 6;
  float acc = 0.0f;
  for (int idx = part; idx < nk; idx += 4) {
    int ko = lo + idx;
    if (ko >= 0) acc += sc[idx] * vbuf[(long)(b * Tc + ko) * 128 + g * HDc + d];
  }
  pacc[part][d] = acc;
  __syncthreads();
  if (tid < HDc) {
    float o = (pacc[0][tid] + pacc[1][tid] + pacc[2][tid] + pacc[3][tid]) / denom;
    out[(long)(b * Tc + qo) * Dc + h * HDc + tid] = o;
  }
}

// ---------------- elementwise ----------------
__global__ void k_glu_conv(float* __restrict__ h, int n) {
  int i = blockIdx.x * 256 + threadIdx.x;
  if (i >= n) return;
  int r = i >> 9, j = i & 511;
  float a = h[(long)r * 1024 + j], g = h[(long)r * 1024 + 512 + j];
  h[(long)r * 1024 + j] = a * (1.0f / (1.0f + __expf(-g)));
}
__global__ void k_swiglu(float* __restrict__ h, int n) {
  int i = blockIdx.x * 256 + threadIdx.x;
  if (i >= n) return;
  int r = i >> 10, j = i & 1023;
  float a = h[(long)r * 2048 + j], bb = h[(long)r * 2048 + 1024 + j];
  h[(long)r * 2048 + j] = (a / (1.0f + __expf(-a))) * bb;
}
__global__ void k_dwconv(const float* __restrict__ in, const void* __restrict__ dw, long doff,
                         float* __restrict__ out, int n, const int* __restrict__ flag) {
  int f32 = flag[0];
  int i = blockIdx.x * 256 + threadIdx.x;
  if (i >= n) return;
  int d = i & 511;
  int t = (i >> 9) & (Tc - 1);
  int b = i >> 19;
  float acc = 0.0f;
#pragma unroll
  for (int j = 0; j < 9; ++j) {
    int tt = t + j - 4;
    if (tt >= 0 && tt < Tc) acc += in[((long)(b * Tc + tt) << 10) + d] * wload(dw, doff + d * 9 + j, f32);
  }
  out[i] = acc * (1.0f / (1.0f + __expf(-acc)));
}

extern "C" void kernel_launch(void* const* d_in, const int* in_sizes, int n_in,
                              void* d_out, int out_size, void* d_ws, size_t ws_size,
                              hipStream_t stream) {
  const void* x_in = d_in[0];
  const int*  alen = (const int*)d_in[1];
  const void* ln1w = d_in[2];
  const void* ln1b = d_in[3];
  const void* wq   = d_in[4];
  const void* wk   = d_in[5];
  const void* wv   = d_in[6];
  const void* wo   = d_in[7];
  const void* rel  = d_in[8];
  const void* ln2w = d_in[9];
  const void* ln2b = d_in[10];
  const void* pw1  = d_in[11];
  const void* dwv  = d_in[12];
  const void* pw2  = d_in[13];
  const void* ln3w = d_in[14];
  const void* ln3b = d_in[15];
  const void* w1   = d_in[16];
  const void* w2   = d_in[17];

  int*   flag = (int*)d_ws;
  float* xf  = (float*)((char*)d_ws + 256);
  float* lnb = xf + NE;
  float* big = lnb + NE;
  float* qb = xf;
  float* kb = big;
  float* vb = big + (long)NBT * 128;
  float* ab = big + (long)NBT * 256;
  float* cb = big + (long)NBT * 1024;
  bf16* Rqbuf = (bf16*)((char*)d_ws + 256 + NE * 3 * 4 + (long)NBT * 2048 * 4);
  bool rq_ok = ws_size >= (size_t)(256 + NE * 3 * 4 + (long)NBT * 2048 * 4 + (long)32 * Tc * 384 * 2);

  k_detect<<<1, 256, 0, stream>>>(x_in, flag);
  k_in<<<(int)((NE + 255) / 256), 256, 0, stream>>>(x_in, xf, (int)NE, flag);

  for (int i = 0; i < 4; ++i) {
    long oQ = (long)i * Dc * Dc;
    long oKV = (long)i * 128 * Dc;
    long oR = (long)i * (2 * MPc - 1) * HDc;
    long oP1 = (long)i * 1024 * Dc;
    long oDW = (long)i * Dc * 9;
    long oF1 = (long)i * 2048 * Dc;
    long oF2 = (long)i * Dc * 1024;
    long oLN = (long)i * Dc;

    // ---- attention ----
    k_ln<<<NBT, 256, 0, stream>>>(xf, ln1w, ln1b, oLN, lnb, flag);
    k_gemm_m<<<dim3(4, 32), 256, 0, stream>>>(lnb, Dc, wq, oQ, qb, Dc, nullptr, 0.125f, 512, 512, flag);
    k_gemm_m<<<dim3(1, 32), 256, 0, stream>>>(lnb, Dc, wk, oKV, kb, 128, nullptr, 1.0f, 128, 512, flag);
    k_gemm_m<<<dim3(1, 32), 256, 0, stream>>>(lnb, Dc, wv, oKV, vb, 128, nullptr, 1.0f, 128, 512, flag);
    if (rq_ok) {
      k_rq_m<<<dim3(3, 8, 32), 256, 0, stream>>>(qb, rel, oR, Rqbuf, flag);
      k_attn_chunk<<<dim3(16, 8, 4), 256, 0, stream>>>(qb, kb, vb, Rqbuf, alen, ab);
      k_attn_inv<<<dim3(16, 8, 4), 256, 0, stream>>>(qb, kb, vb, Rqbuf, alen, ab);
    } else {
      k_attn<<<dim3(Tc, Hc, Bc), 256, 0, stream>>>(qb, kb, vb, rel, oR, alen, ab, flag);
    }
    k_gemm_m<<<dim3(4, 32), 256, 0, stream>>>(ab, Dc, wo, oQ, xf, Dc, lnb, 1.0f, 512, 512, flag);

    // ---- conv ----
    k_ln<<<NBT, 256, 0, stream>>>(xf, ln2w, ln2b, oLN, lnb, flag);
    k_gemm_m<<<dim3(8, 32), 256, 0, stream>>>(lnb, Dc, pw1, oP1, big, 1024, nullptr, 1.0f, 1024, 512, flag);
    k_glu_conv<<<NBT * 512 / 256, 256, 0, stream>>>(big, NBT * 512);
    k_dwconv<<<NBT * 512 / 256, 256, 0, stream>>>(big, dwv, oDW, cb, NBT * 512, flag);
    k_gemm_m<<<dim3(4, 32), 256, 0, stream>>>(cb, 512, pw2, oQ, xf, Dc, lnb, 1.0f, 512, 512, flag);

    // ---- ffn ----
    k_ln<<<NBT, 256, 0, stream>>>(xf, ln3w, ln3b, oLN, lnb, flag);
    k_gemm_m<<<dim3(16, 32), 256, 0, stream>>>(lnb, Dc, w1, oF1, big, 2048, nullptr, 1.0f, 2048, 512, flag);
    k_swiglu<<<NBT * 1024 / 256, 256, 0, stream>>>(big, NBT * 1024);
    k_gemm_m<<<dim3(4, 32), 256, 0, stream>>>(big, 2048, w2, oF2, xf, Dc, lnb, 1.0f, 512, 1024, flag);
  }

  k_out<<<(int)((NE + 255) / 256), 256, 0, stream>>>(xf, d_out, (int)NE, flag);
}

// Round 6
// 1780.944 us; speedup vs baseline: 6.0359x; 1.4097x over previous
//
#include <hip/hip_runtime.h>
#include <hip/hip_bf16.h>

typedef __hip_bfloat16 bf16;
typedef unsigned short ushort_t;
typedef unsigned int uint_t;
typedef __attribute__((ext_vector_type(8))) short short8;
typedef __attribute__((ext_vector_type(4))) float floatx4;

__device__ __forceinline__ float b2f(bf16 x) { return __bfloat162float(x); }
__device__ __forceinline__ ushort_t f2us(float f) { bf16 h = __float2bfloat16(f); return *(ushort_t*)&h; }
__device__ __forceinline__ float us2f(ushort_t u) { return __uint_as_float(((uint_t)u) << 16); }

constexpr int Bc = 4, Tc = 1024, Dc = 512, Hc = 8, HDc = 64;
constexpr int LCc = 128, MPc = 192;
constexpr float EPSc = 1e-4f;
constexpr int NBT = Bc * Tc;
constexpr long NE = (long)NBT * Dc;
constexpr float NEGB = -1e30f;

__device__ __forceinline__ float wload(const void* p, long i, int f32) {
  return f32 ? ((const float*)p)[i] : b2f(((const bf16*)p)[i]);
}

// ---------------- dtype detector ----------------
__global__ void k_detect(const void* __restrict__ x, int* __restrict__ flag) {
  __shared__ int s[256];
  int t = threadIdx.x;
  const unsigned short* u = (const unsigned short*)x;
  int bad = 0;
  for (int j = t; j < 2048; j += 256) {
    int e = (u[j] >> 7) & 0xFF;
    if (e == 0xFF || e > 0x8F || (e != 0 && e < 0x6F)) bad++;
  }
  s[t] = bad;
  __syncthreads();
  for (int off = 128; off > 0; off >>= 1) { if (t < off) s[t] += s[t + off]; __syncthreads(); }
  if (t == 0) flag[0] = (s[0] > 16) ? 1 : 0;
}

__global__ void k_in(const void* __restrict__ in, float* __restrict__ out, int n,
                     const int* __restrict__ flag) {
  int i = blockIdx.x * 256 + threadIdx.x;
  if (i < n) out[i] = wload(in, i, flag[0]);
}
__global__ void k_out(const float* __restrict__ in, void* __restrict__ out, int n,
                      const int* __restrict__ flag) {
  int i = blockIdx.x * 256 + threadIdx.x;
  if (i >= n) return;
  if (flag[0]) ((float*)out)[i] = in[i];
  else         ((bf16*)out)[i] = __float2bfloat16(in[i]);
}

// ---------------- LayerNorm ----------------
__global__ __launch_bounds__(256) void k_ln(const float* __restrict__ x,
    const void* __restrict__ w, const void* __restrict__ bb, long woff,
    float* __restrict__ o, const int* __restrict__ flag) {
  int f32 = flag[0];
  int row = blockIdx.x;
  int t = threadIdx.x;
  const float* xr = x + (long)row * Dc;
  float x0 = xr[t], x1 = xr[t + 256];
  __shared__ float red[256];
  red[t] = x0 + x1;
  __syncthreads();
  for (int off = 128; off > 0; off >>= 1) { if (t < off) red[t] += red[t + off]; __syncthreads(); }
  float mean = red[0] * (1.0f / Dc);
  __syncthreads();
  float d0 = x0 - mean, d1 = x1 - mean;
  red[t] = d0 * d0 + d1 * d1;
  __syncthreads();
  for (int off = 128; off > 0; off >>= 1) { if (t < off) red[t] += red[t + off]; __syncthreads(); }
  float inv = 1.0f / sqrtf(red[0] * (1.0f / Dc) + EPSc);
  float* orow = o + (long)row * Dc;
  orow[t]       = d0 * inv * wload(w, woff + t, f32)       + wload(bb, woff + t, f32);
  orow[t + 256] = d1 * inv * wload(w, woff + t + 256, f32) + wload(bb, woff + t + 256, f32);
}

// ---------------- MFMA GEMM ----------------
__global__ __launch_bounds__(256) void k_gemm_m(const float* __restrict__ A, int lda,
    const void* __restrict__ W, long woff, float* __restrict__ C, int ldc,
    const float* __restrict__ addend, float alpha, int N, int K,
    const int* __restrict__ flag) {
  int f32 = flag[0];
  __shared__ ushort_t As[128 * 40];
  __shared__ ushort_t Ws[128 * 40];
  int tid = threadIdx.x;
  int m0 = blockIdx.y * 128, n0 = blockIdx.x * 128;
  int r = tid >> 1, hc = (tid & 1) * 16;
  int lane = tid & 63, wv = tid >> 6;
  int wm = (wv >> 1) * 64, wn = (wv & 1) * 64;
  int l15 = lane & 15, quad = lane >> 4;
  floatx4 acc[4][4];
#pragma unroll
  for (int i = 0; i < 4; ++i)
#pragma unroll
    for (int j = 0; j < 4; ++j) acc[i][j] = 0;
  for (int k0 = 0; k0 < K; k0 += 32) {
    {
      const float* Ap = A + (long)(m0 + r) * lda + k0 + hc;
      ushort_t tmp[16];
#pragma unroll
      for (int u = 0; u < 4; ++u) {
        float4 v = *(const float4*)(Ap + u * 4);
        tmp[u * 4 + 0] = f2us(v.x); tmp[u * 4 + 1] = f2us(v.y);
        tmp[u * 4 + 2] = f2us(v.z); tmp[u * 4 + 3] = f2us(v.w);
      }
      *(uint4*)&As[r * 40 + hc] = *(uint4*)&tmp[0];
      *(uint4*)&As[r * 40 + hc + 8] = *(uint4*)&tmp[8];
    }
    {
      long wb = woff + (long)(n0 + r) * K + k0 + hc;
      if (f32) {
        const float* Wp = (const float*)W + wb;
        ushort_t tmp[16];
#pragma unroll
        for (int u = 0; u < 4; ++u) {
          float4 v = *(const float4*)(Wp + u * 4);
          tmp[u * 4 + 0] = f2us(v.x); tmp[u * 4 + 1] = f2us(v.y);
          tmp[u * 4 + 2] = f2us(v.z); tmp[u * 4 + 3] = f2us(v.w);
        }
        *(uint4*)&Ws[r * 40 + hc] = *(uint4*)&tmp[0];
        *(uint4*)&Ws[r * 40 + hc + 8] = *(uint4*)&tmp[8];
      } else {
        const ushort_t* Wp = (const ushort_t*)W + wb;
        *(uint4*)&Ws[r * 40 + hc] = *(const uint4*)(Wp);
        *(uint4*)&Ws[r * 40 + hc + 8] = *(const uint4*)(Wp + 8);
      }
    }
    __syncthreads();
    short8 af[4], bfr[4];
#pragma unroll
    for (int i = 0; i < 4; ++i) af[i] = *(short8*)&As[(wm + i * 16 + l15) * 40 + quad * 8];
#pragma unroll
    for (int j = 0; j < 4; ++j) bfr[j] = *(short8*)&Ws[(wn + j * 16 + l15) * 40 + quad * 8];
#pragma unroll
    for (int i = 0; i < 4; ++i)
#pragma unroll
      for (int j = 0; j < 4; ++j)
        acc[i][j] = __builtin_amdgcn_mfma_f32_16x16x32_bf16(af[i], bfr[j], acc[i][j], 0, 0, 0);
    __syncthreads();
  }
#pragma unroll
  for (int i = 0; i < 4; ++i) {
#pragma unroll
    for (int j = 0; j < 4; ++j) {
#pragma unroll
      for (int rg = 0; rg < 4; ++rg) {
        int m = m0 + wm + i * 16 + quad * 4 + rg;
        int n = n0 + wn + j * 16 + l15;
        float v = alpha * acc[i][j][rg];
        if (addend) v += addend[(long)m * ldc + n];
        C[(long)m * ldc + n] = v;
      }
    }
  }
}

// ---------------- MFMA Rq ----------------
__global__ __launch_bounds__(256) void k_rq_m(const float* __restrict__ qb,
    const void* __restrict__ rel, long roff, bf16* __restrict__ Rq,
    const int* __restrict__ flag) {
  int f32 = flag[0];
  __shared__ ushort_t As[128 * 40];
  __shared__ ushort_t Ws[128 * 40];
  int tid = threadIdx.x;
  int bh = blockIdx.z;
  const float* A = qb + (long)(bh >> 3) * Tc * Dc + (bh & 7) * 64;
  int m0 = blockIdx.y * 128, n0 = blockIdx.x * 128;
  int r = tid >> 1, hc = (tid & 1) * 16;
  int lane = tid & 63, wv = tid >> 6;
  int wm = (wv >> 1) * 64, wn = (wv & 1) * 64;
  int l15 = lane & 15, quad = lane >> 4;
  floatx4 acc[4][4];
#pragma unroll
  for (int i = 0; i < 4; ++i)
#pragma unroll
    for (int j = 0; j < 4; ++j) acc[i][j] = 0;
  for (int k0 = 0; k0 < 64; k0 += 32) {
    {
      const float* Ap = A + (long)(m0 + r) * Dc + k0 + hc;
      ushort_t tmp[16];
#pragma unroll
      for (int u = 0; u < 4; ++u) {
        float4 v = *(const float4*)(Ap + u * 4);
        tmp[u * 4 + 0] = f2us(v.x); tmp[u * 4 + 1] = f2us(v.y);
        tmp[u * 4 + 2] = f2us(v.z); tmp[u * 4 + 3] = f2us(v.w);
      }
      *(uint4*)&As[r * 40 + hc] = *(uint4*)&tmp[0];
      *(uint4*)&As[r * 40 + hc + 8] = *(uint4*)&tmp[8];
    }
    {
      int wr = n0 + r; if (wr > 382) wr = 382;
      long wb = roff + (long)wr * 64 + k0 + hc;
      if (f32) {
        const float* Wp = (const float*)rel + wb;
        ushort_t tmp[16];
#pragma unroll
        for (int u = 0; u < 4; ++u) {
          float4 v = *(const float4*)(Wp + u * 4);
          tmp[u * 4 + 0] = f2us(v.x); tmp[u * 4 + 1] = f2us(v.y);
          tmp[u * 4 + 2] = f2us(v.z); tmp[u * 4 + 3] = f2us(v.w);
        }
        *(uint4*)&Ws[r * 40 + hc] = *(uint4*)&tmp[0];
        *(uint4*)&Ws[r * 40 + hc + 8] = *(uint4*)&tmp[8];
      } else {
        const ushort_t* Wp = (const ushort_t*)rel + wb;
        *(uint4*)&Ws[r * 40 + hc] = *(const uint4*)(Wp);
        *(uint4*)&Ws[r * 40 + hc + 8] = *(const uint4*)(Wp + 8);
      }
    }
    __syncthreads();
    short8 af[4], bfr[4];
#pragma unroll
    for (int i = 0; i < 4; ++i) af[i] = *(short8*)&As[(wm + i * 16 + l15) * 40 + quad * 8];
#pragma unroll
    for (int j = 0; j < 4; ++j) bfr[j] = *(short8*)&Ws[(wn + j * 16 + l15) * 40 + quad * 8];
#pragma unroll
    for (int i = 0; i < 4; ++i)
#pragma unroll
      for (int j = 0; j < 4; ++j)
        acc[i][j] = __builtin_amdgcn_mfma_f32_16x16x32_bf16(af[i], bfr[j], acc[i][j], 0, 0, 0);
    __syncthreads();
  }
#pragma unroll
  for (int i = 0; i < 4; ++i) {
#pragma unroll
    for (int j = 0; j < 4; ++j) {
      int n = n0 + wn + j * 16 + l15;
      if (n >= 384) continue;
#pragma unroll
      for (int rg = 0; rg < 4; ++rg) {
        int m = m0 + wm + i * 16 + quad * 4 + rg;
        Rq[((long)bh * Tc + m) * 384 + n] = __float2bfloat16(acc[i][j][rg]);
      }
    }
  }
}

// ---------------- MFMA flash attention (both valid-window and invalid-full paths) ----------------
// 64 queries/block, 4 waves x 16 queries. K-tiles of 64. Q/K [row][72] bf16 LDS,
// V transposed [d][72], P per-wave [query][72] (same-wave LDS round trip, no barrier).
// INV=false: 3-tile window [q0-128,q0+64), mask ko>=len, write rows qi<nvalid.
// INV=true : 18 tiles full, no mask, write rows qi>=nskip.
template<bool INV>
__global__ __launch_bounds__(256) void k_attn_flash(const float* __restrict__ q,
    const float* __restrict__ kb, const float* __restrict__ vb,
    const bf16* __restrict__ Rq, const int* __restrict__ alen, float* __restrict__ out) {
  int qt = blockIdx.x, h = blockIdx.y, b = blockIdx.z;
  int len = alen[b];
  int q0 = qt * 64;
  if (INV) { if (q0 + 64 <= len) return; }
  else     { if (q0 >= len) return; }
  int nskip = max(len - q0, 0);          // INV: write qi >= nskip
  int nvalid = min(len - q0, 64);        // !INV: write qi < nvalid
  int g = h >> 2;
  __shared__ __align__(16) ushort_t Qs[64 * 72];
  __shared__ __align__(16) ushort_t Ks[64 * 72];
  __shared__ __align__(16) ushort_t Vt[64 * 72];
  __shared__ __align__(16) ushort_t Ps[64 * 72];
  int t = threadIdx.x;
  int lane = t & 63, w = t >> 6;
  int l15 = lane & 15, quad = lane >> 4;
  int qw = w * 16;
  {
    int qi = t >> 2, du = (t & 3) * 16;
    const float* src = &q[((long)(b * Tc + q0 + qi)) * Dc + h * 64 + du];
    ushort_t tmp[16];
#pragma unroll
    for (int u = 0; u < 4; ++u) {
      float4 v = *(const float4*)(src + u * 4);
      tmp[u * 4 + 0] = f2us(v.x); tmp[u * 4 + 1] = f2us(v.y);
      tmp[u * 4 + 2] = f2us(v.z); tmp[u * 4 + 3] = f2us(v.w);
    }
    *(uint4*)&Qs[qi * 72 + du] = *(uint4*)&tmp[0];
    *(uint4*)&Qs[qi * 72 + du + 8] = *(uint4*)&tmp[8];
  }
  float m_[4], l_[4], alpha[4];
  floatx4 acc[4];
#pragma unroll
  for (int r = 0; r < 4; ++r) { m_[r] = NEGB; l_[r] = 0.f; acc[r] = 0; }
  const ushort_t* Rqu = (const ushort_t*)Rq;
  long rqrow = (long)(b * 8 + h) * Tc + q0;
  const int NT = INV ? 18 : 3;
  for (int kt = 0; kt < NT; ++kt) {
    int ko0 = INV ? (kt * 64 - 128) : (q0 - 128 + kt * 64);
    __syncthreads();
    {
      int kj = t >> 2, du = (t & 3) * 16;
      int ko = ko0 + kj;
      ushort_t tk[16], tv[16];
      if (ko >= 0) {
        long base = ((long)(b * Tc + ko)) * 128 + g * 64 + du;
#pragma unroll
        for (int u = 0; u < 4; ++u) {
          float4 k4 = *(const float4*)&kb[base + u * 4];
          float4 v4 = *(const float4*)&vb[base + u * 4];
          tk[u * 4 + 0] = f2us(k4.x); tk[u * 4 + 1] = f2us(k4.y);
          tk[u * 4 + 2] = f2us(k4.z); tk[u * 4 + 3] = f2us(k4.w);
          tv[u * 4 + 0] = f2us(v4.x); tv[u * 4 + 1] = f2us(v4.y);
          tv[u * 4 + 2] = f2us(v4.z); tv[u * 4 + 3] = f2us(v4.w);
        }
      } else {
#pragma unroll
        for (int u = 0; u < 16; ++u) { tk[u] = 0; tv[u] = 0; }
      }
      *(uint4*)&Ks[kj * 72 + du] = *(uint4*)&tk[0];
      *(uint4*)&Ks[kj * 72 + du + 8] = *(uint4*)&tk[8];
#pragma unroll
      for (int u = 0; u < 16; ++u) Vt[(du + u) * 72 + kj] = tv[u];
    }
    __syncthreads();
    short8 aq0 = *(short8*)&Qs[(qw + l15) * 72 + quad * 8];
    short8 aq1 = *(short8*)&Qs[(qw + l15) * 72 + 32 + quad * 8];
    floatx4 s[4];
#pragma unroll
    for (int nt = 0; nt < 4; ++nt) {
      short8 bk0 = *(short8*)&Ks[(nt * 16 + l15) * 72 + quad * 8];
      short8 bk1 = *(short8*)&Ks[(nt * 16 + l15) * 72 + 32 + quad * 8];
      floatx4 z = {0.f, 0.f, 0.f, 0.f};
      z = __builtin_amdgcn_mfma_f32_16x16x32_bf16(aq0, bk0, z, 0, 0, 0);
      z = __builtin_amdgcn_mfma_f32_16x16x32_bf16(aq1, bk1, z, 0, 0, 0);
      s[nt] = z;
    }
    // rel bias (Rq table) + mask
#pragma unroll
    for (int nt = 0; nt < 4; ++nt) {
      int ko = ko0 + nt * 16 + l15;
      bool msk = (!INV) && (ko >= len);
#pragma unroll
      for (int r = 0; r < 4; ++r) {
        int qi = qw + quad * 4 + r;
        int dist = (q0 + qi) - ko;
        dist = min(max(dist, -(MPc - 1)), MPc - 1);
        float rv = us2f(Rqu[(rqrow + qi) * 384 + dist + 191]);
        s[nt][r] = msk ? NEGB : (s[nt][r] + rv);
      }
    }
    // online softmax per row (row = quad*4+r, spread across 16 l15 lanes)
#pragma unroll
    for (int r = 0; r < 4; ++r) {
      float mx = fmaxf(fmaxf(s[0][r], s[1][r]), fmaxf(s[2][r], s[3][r]));
#pragma unroll
      for (int o = 1; o < 16; o <<= 1) mx = fmaxf(mx, __shfl_xor(mx, o, 64));
      float mn = fmaxf(m_[r], mx);
      alpha[r] = __expf(m_[r] - mn);
      float p0 = __expf(s[0][r] - mn), p1 = __expf(s[1][r] - mn);
      float p2 = __expf(s[2][r] - mn), p3 = __expf(s[3][r] - mn);
      s[0][r] = p0; s[1][r] = p1; s[2][r] = p2; s[3][r] = p3;
      float ps = p0 + p1 + p2 + p3;
#pragma unroll
      for (int o = 1; o < 16; o <<= 1) ps += __shfl_xor(ps, o, 64);
      l_[r] = l_[r] * alpha[r] + ps;
      m_[r] = mn;
    }
    // P -> LDS (per-wave region of Ps; same-wave write->read, no barrier needed)
#pragma unroll
    for (int nt = 0; nt < 4; ++nt)
#pragma unroll
      for (int r = 0; r < 4; ++r)
        Ps[(qw + quad * 4 + r) * 72 + nt * 16 + l15] = f2us(s[nt][r]);
    // rescale acc
#pragma unroll
    for (int j = 0; j < 4; ++j)
#pragma unroll
      for (int r = 0; r < 4; ++r) acc[j][r] *= alpha[r];
    // PV
    short8 ap0 = *(short8*)&Ps[(qw + l15) * 72 + quad * 8];
    short8 ap1 = *(short8*)&Ps[(qw + l15) * 72 + 32 + quad * 8];
#pragma unroll
    for (int j = 0; j < 4; ++j) {
      short8 bv0 = *(short8*)&Vt[(j * 16 + l15) * 72 + quad * 8];
      short8 bv1 = *(short8*)&Vt[(j * 16 + l15) * 72 + 32 + quad * 8];
      acc[j] = __builtin_amdgcn_mfma_f32_16x16x32_bf16(ap0, bv0, acc[j], 0, 0, 0);
      acc[j] = __builtin_amdgcn_mfma_f32_16x16x32_bf16(ap1, bv1, acc[j], 0, 0, 0);
    }
  }
#pragma unroll
  for (int r = 0; r < 4; ++r) {
    int qi = qw + quad * 4 + r;
    bool wr = INV ? (qi >= nskip) : (qi < nvalid);
    if (wr) {
      float inv = 1.0f / l_[r];
#pragma unroll
      for (int j = 0; j < 4; ++j)
        out[((long)(b * Tc + q0 + qi)) * Dc + h * 64 + j * 16 + l15] = acc[j][r] * inv;
    }
  }
}

// ---------------- Fallback attention (ws-too-small path) ----------------
__global__ __launch_bounds__(256) void k_attn(const float* __restrict__ q,
    const float* __restrict__ kbuf, const float* __restrict__ vbuf,
    const void* __restrict__ rel, long roff, const int* __restrict__ alen,
    float* __restrict__ out, const int* __restrict__ flag) {
  int f32 = flag[0];
  int qo = blockIdx.x, h = blockIdx.y, b = blockIdx.z;
  int g = h >> 2;
  int len = alen[b];
  int tid = threadIdx.x;
  __shared__ float qs[HDc];
  __shared__ float sc[Tc + LCc];
  __shared__ float red[256];
  __shared__ float pacc[4][HDc];
  if (tid < HDc) qs[tid] = q[(long)(b * Tc + qo) * Dc + h * HDc + tid];
  __syncthreads();
  bool vq = qo < len;
  int lo, hi;
  if (vq) { int c = (qo >> 6) << 6; lo = c - LCc; hi = c + 64; }
  else    { lo = -LCc; hi = Tc; }
  int nk = hi - lo;
  for (int idx = tid; idx < nk; idx += 256) {
    int ko = lo + idx;
    float s;
    if (vq && ko >= len) {
      s = NEGB;
    } else {
      s = 0.0f;
      if (ko >= 0) {
        const float* kr = kbuf + (long)(b * Tc + ko) * 128 + g * HDc;
#pragma unroll
        for (int d = 0; d < HDc; ++d) s += qs[d] * kr[d];
      }
      int dist = qo - ko;
      if (dist > MPc - 1) dist = MPc - 1;
      if (dist < -(MPc - 1)) dist = -(MPc - 1);
      long rb = roff + (long)(dist + MPc - 1) * HDc;
#pragma unroll
      for (int d = 0; d < HDc; ++d) s += qs[d] * wload(rel, rb + d, f32);
    }
    sc[idx] = s;
  }
  __syncthreads();
  float lm = NEGB;
  for (int idx = tid; idx < nk; idx += 256) lm = fmaxf(lm, sc[idx]);
  red[tid] = lm;
  __syncthreads();
  for (int off = 128; off > 0; off >>= 1) { if (tid < off) red[tid] = fmaxf(red[tid], red[tid + off]); __syncthreads(); }
  float mx = red[0];
  __syncthreads();
  float ls = 0.0f;
  for (int idx = tid; idx < nk; idx += 256) { float p = __expf(sc[idx] - mx); sc[idx] = p; ls += p; }
  red[tid] = ls;
  __syncthreads();
  for (int off = 128; off > 0; off >>= 1) { if (tid < off) red[tid] += red[tid + off]; __syncthreads(); }
  float denom = red[0];
  __syncthreads();
  int d = tid & 63, part = tid >> 6;
  float acc = 0.0f;
  for (int idx = part; idx < nk; idx += 4) {
    int ko = lo + idx;
    if (ko >= 0) acc += sc[idx] * vbuf[(long)(b * Tc + ko) * 128 + g * HDc + d];
  }
  pacc[part][d] = acc;
  __syncthreads();
  if (tid < HDc) {
    float o = (pacc[0][tid] + pacc[1][tid] + pacc[2][tid] + pacc[3][tid]) / denom;
    out[(long)(b * Tc + qo) * Dc + h * HDc + tid] = o;
  }
}

// ---------------- elementwise ----------------
__global__ void k_glu_conv(float* __restrict__ h, int n) {
  int i = blockIdx.x * 256 + threadIdx.x;
  if (i >= n) return;
  int r = i >> 9, j = i & 511;
  float a = h[(long)r * 1024 + j], g = h[(long)r * 1024 + 512 + j];
  h[(long)r * 1024 + j] = a * (1.0f / (1.0f + __expf(-g)));
}
__global__ void k_swiglu(float* __restrict__ h, int n) {
  int i = blockIdx.x * 256 + threadIdx.x;
  if (i >= n) return;
  int r = i >> 10, j = i & 1023;
  float a = h[(long)r * 2048 + j], bb = h[(long)r * 2048 + 1024 + j];
  h[(long)r * 2048 + j] = (a / (1.0f + __expf(-a))) * bb;
}
__global__ void k_dwconv(const float* __restrict__ in, const void* __restrict__ dw, long doff,
                         float* __restrict__ out, int n, const int* __restrict__ flag) {
  int f32 = flag[0];
  int i = blockIdx.x * 256 + threadIdx.x;
  if (i >= n) return;
  int d = i & 511;
  int t = (i >> 9) & (Tc - 1);
  int b = i >> 19;
  float acc = 0.0f;
#pragma unroll
  for (int j = 0; j < 9; ++j) {
    int tt = t + j - 4;
    if (tt >= 0 && tt < Tc) acc += in[((long)(b * Tc + tt) << 10) + d] * wload(dw, doff + d * 9 + j, f32);
  }
  out[i] = acc * (1.0f / (1.0f + __expf(-acc)));
}

extern "C" void kernel_launch(void* const* d_in, const int* in_sizes, int n_in,
                              void* d_out, int out_size, void* d_ws, size_t ws_size,
                              hipStream_t stream) {
  const void* x_in = d_in[0];
  const int*  alen = (const int*)d_in[1];
  const void* ln1w = d_in[2];
  const void* ln1b = d_in[3];
  const void* wq   = d_in[4];
  const void* wk   = d_in[5];
  const void* wv   = d_in[6];
  const void* wo   = d_in[7];
  const void* rel  = d_in[8];
  const void* ln2w = d_in[9];
  const void* ln2b = d_in[10];
  const void* pw1  = d_in[11];
  const void* dwv  = d_in[12];
  const void* pw2  = d_in[13];
  const void* ln3w = d_in[14];
  const void* ln3b = d_in[15];
  const void* w1   = d_in[16];
  const void* w2   = d_in[17];

  int*   flag = (int*)d_ws;
  float* xf  = (float*)((char*)d_ws + 256);
  float* lnb = xf + NE;
  float* big = lnb + NE;
  float* qb = xf;
  float* kb = big;
  float* vb = big + (long)NBT * 128;
  float* ab = big + (long)NBT * 256;
  float* cb = big + (long)NBT * 1024;
  bf16* Rqbuf = (bf16*)((char*)d_ws + 256 + NE * 3 * 4 + (long)NBT * 2048 * 4);
  bool rq_ok = ws_size >= (size_t)(256 + NE * 3 * 4 + (long)NBT * 2048 * 4 + (long)32 * Tc * 384 * 2);

  k_detect<<<1, 256, 0, stream>>>(x_in, flag);
  k_in<<<(int)((NE + 255) / 256), 256, 0, stream>>>(x_in, xf, (int)NE, flag);

  for (int i = 0; i < 4; ++i) {
    long oQ = (long)i * Dc * Dc;
    long oKV = (long)i * 128 * Dc;
    long oR = (long)i * (2 * MPc - 1) * HDc;
    long oP1 = (long)i * 1024 * Dc;
    long oDW = (long)i * Dc * 9;
    long oF1 = (long)i * 2048 * Dc;
    long oF2 = (long)i * Dc * 1024;
    long oLN = (long)i * Dc;

    // ---- attention ----
    k_ln<<<NBT, 256, 0, stream>>>(xf, ln1w, ln1b, oLN, lnb, flag);
    k_gemm_m<<<dim3(4, 32), 256, 0, stream>>>(lnb, Dc, wq, oQ, qb, Dc, nullptr, 0.125f, 512, 512, flag);
    k_gemm_m<<<dim3(1, 32), 256, 0, stream>>>(lnb, Dc, wk, oKV, kb, 128, nullptr, 1.0f, 128, 512, flag);
    k_gemm_m<<<dim3(1, 32), 256, 0, stream>>>(lnb, Dc, wv, oKV, vb, 128, nullptr, 1.0f, 128, 512, flag);
    if (rq_ok) {
      k_rq_m<<<dim3(3, 8, 32), 256, 0, stream>>>(qb, rel, oR, Rqbuf, flag);
      k_attn_flash<false><<<dim3(16, 8, 4), 256, 0, stream>>>(qb, kb, vb, Rqbuf, alen, ab);
      k_attn_flash<true><<<dim3(16, 8, 4), 256, 0, stream>>>(qb, kb, vb, Rqbuf, alen, ab);
    } else {
      k_attn<<<dim3(Tc, Hc, Bc), 256, 0, stream>>>(qb, kb, vb, rel, oR, alen, ab, flag);
    }
    k_gemm_m<<<dim3(4, 32), 256, 0, stream>>>(ab, Dc, wo, oQ, xf, Dc, lnb, 1.0f, 512, 512, flag);

    // ---- conv ----
    k_ln<<<NBT, 256, 0, stream>>>(xf, ln2w, ln2b, oLN, lnb, flag);
    k_gemm_m<<<dim3(8, 32), 256, 0, stream>>>(lnb, Dc, pw1, oP1, big, 1024, nullptr, 1.0f, 1024, 512, flag);
    k_glu_conv<<<NBT * 512 / 256, 256, 0, stream>>>(big, NBT * 512);
    k_dwconv<<<NBT * 512 / 256, 256, 0, stream>>>(big, dwv, oDW, cb, NBT * 512, flag);
    k_gemm_m<<<dim3(4, 32), 256, 0, stream>>>(cb, 512, pw2, oQ, xf, Dc, lnb, 1.0f, 512, 512, flag);

    // ---- ffn ----
    k_ln<<<NBT, 256, 0, stream>>>(xf, ln3w, ln3b, oLN, lnb, flag);
    k_gemm_m<<<dim3(16, 32), 256, 0, stream>>>(lnb, Dc, w1, oF1, big, 2048, nullptr, 1.0f, 2048, 512, flag);
    k_swiglu<<<NBT * 1024 / 256, 256, 0, stream>>>(big, NBT * 1024);
    k_gemm_m<<<dim3(4, 32), 256, 0, stream>>>(big, 2048, w2, oF2, xf, Dc, lnb, 1.0f, 512, 1024, flag);
  }

  k_out<<<(int)((NE + 255) / 256), 256, 0, stream>>>(xf, d_out, (int)NE, flag);
}

// Round 7
// 1487.125 us; speedup vs baseline: 7.2284x; 1.1976x over previous
//
#include <hip/hip_runtime.h>
#include <hip/hip_bf16.h>

typedef __hip_bfloat16 bf16;
typedef unsigned short ushort_t;
typedef unsigned int uint_t;
typedef __attribute__((ext_vector_type(8))) short short8;
typedef __attribute__((ext_vector_type(4))) float floatx4;

__device__ __forceinline__ float b2f(bf16 x) { return __bfloat162float(x); }
__device__ __forceinline__ ushort_t f2us(float f) { bf16 h = __float2bfloat16(f); return *(ushort_t*)&h; }
__device__ __forceinline__ float us2f(ushort_t u) { return __uint_as_float(((uint_t)u) << 16); }

constexpr int Bc = 4, Tc = 1024, Dc = 512, Hc = 8, HDc = 64;
constexpr int LCc = 128, MPc = 192;
constexpr float EPSc = 1e-4f;
constexpr int NBT = Bc * Tc;
constexpr long NE = (long)NBT * Dc;
constexpr float NEGB = -1e30f;

__device__ __forceinline__ float wload(const void* p, long i, int f32) {
  return f32 ? ((const float*)p)[i] : b2f(((const bf16*)p)[i]);
}

// ---------------- dtype detector ----------------
__global__ void k_detect(const void* __restrict__ x, int* __restrict__ flag) {
  __shared__ int s[256];
  int t = threadIdx.x;
  const unsigned short* u = (const unsigned short*)x;
  int bad = 0;
  for (int j = t; j < 2048; j += 256) {
    int e = (u[j] >> 7) & 0xFF;
    if (e == 0xFF || e > 0x8F || (e != 0 && e < 0x6F)) bad++;
  }
  s[t] = bad;
  __syncthreads();
  for (int off = 128; off > 0; off >>= 1) { if (t < off) s[t] += s[t + off]; __syncthreads(); }
  if (t == 0) flag[0] = (s[0] > 16) ? 1 : 0;
}

__global__ void k_in(const void* __restrict__ in, float* __restrict__ out, int n,
                     const int* __restrict__ flag) {
  int i = blockIdx.x * 256 + threadIdx.x;
  if (i < n) out[i] = wload(in, i, flag[0]);
}
__global__ void k_out(const float* __restrict__ in, void* __restrict__ out, int n,
                      const int* __restrict__ flag) {
  int i = blockIdx.x * 256 + threadIdx.x;
  if (i >= n) return;
  if (flag[0]) ((float*)out)[i] = in[i];
  else         ((bf16*)out)[i] = __float2bfloat16(in[i]);
}
// convert any weight tensor to bf16 workspace copy
__global__ void k_w2b(const void* __restrict__ src, ushort_t* __restrict__ dst, int n,
                      const int* __restrict__ flag) {
  int i = blockIdx.x * 256 + threadIdx.x;
  if (i < n) dst[i] = f2us(wload(src, i, flag[0]));
}

// ---------------- LayerNorm: writes f32 (residual addend) + bf16 (GEMM A) ----------------
__global__ __launch_bounds__(256) void k_ln(const float* __restrict__ x,
    const void* __restrict__ w, const void* __restrict__ bb, long woff,
    float* __restrict__ o, ushort_t* __restrict__ oA, const int* __restrict__ flag) {
  int f32 = flag[0];
  int row = blockIdx.x;
  int t = threadIdx.x;
  const float* xr = x + (long)row * Dc;
  float x0 = xr[t], x1 = xr[t + 256];
  __shared__ float red[256];
  red[t] = x0 + x1;
  __syncthreads();
  for (int off = 128; off > 0; off >>= 1) { if (t < off) red[t] += red[t + off]; __syncthreads(); }
  float mean = red[0] * (1.0f / Dc);
  __syncthreads();
  float d0 = x0 - mean, d1 = x1 - mean;
  red[t] = d0 * d0 + d1 * d1;
  __syncthreads();
  for (int off = 128; off > 0; off >>= 1) { if (t < off) red[t] += red[t + off]; __syncthreads(); }
  float inv = 1.0f / sqrtf(red[0] * (1.0f / Dc) + EPSc);
  float v0 = d0 * inv * wload(w, woff + t, f32)       + wload(bb, woff + t, f32);
  float v1 = d1 * inv * wload(w, woff + t + 256, f32) + wload(bb, woff + t + 256, f32);
  float* orow = o + (long)row * Dc;
  ushort_t* arow = oA + (long)row * Dc;
  orow[t] = v0; orow[t + 256] = v1;
  arow[t] = f2us(v0); arow[t + 256] = f2us(v1);
}

// ---------------- bf16 MFMA GEMM: C = alpha*A@W^T (+f32 addend) ----------------
// BK=64, XOR-swizzled LDS (no padding): LDS chunk slot c^(r&7) holds global 16B-chunk c.
// Frag reads are 2-way bank aliased (free); staging is fully coalesced.
template<int BM, int BN, bool OBF>
__global__ __launch_bounds__(256) void k_gemm_b(const ushort_t* __restrict__ A, int lda,
    const ushort_t* __restrict__ W, void* __restrict__ C, int ldc,
    const float* __restrict__ addend, float alpha, int K) {
  constexpr int WGM = BM / 64;          // waves along M
  constexpr int WGN = 4 / WGM;
  constexpr int WN = BN / WGN;
  constexpr int NJ = WN / 16;
  __shared__ ushort_t As[BM * 64];
  __shared__ ushort_t Ws[BN * 64];
  int t = threadIdx.x;
  int m0 = blockIdx.y * BM, n0 = blockIdx.x * BN;
  int lane = t & 63, wv = t >> 6;
  int l15 = lane & 15, quad = lane >> 4;
  int wrow = (WGM == 2) ? (wv >> 1) * 64 : 0;
  int wcol = (WGM == 2) ? (wv & 1) * WN : wv * WN;
  floatx4 acc[4][NJ];
#pragma unroll
  for (int i = 0; i < 4; ++i)
#pragma unroll
    for (int j = 0; j < NJ; ++j) acc[i][j] = 0;
  for (int k0 = 0; k0 < K; k0 += 64) {
#pragma unroll
    for (int i = t; i < BM * 8; i += 256) {
      int r = i >> 3, c = i & 7;
      uint4 v = *(const uint4*)(A + (long)(m0 + r) * lda + k0 + c * 8);
      *(uint4*)&As[r * 64 + ((c ^ (r & 7)) << 3)] = v;
    }
#pragma unroll
    for (int i = t; i < BN * 8; i += 256) {
      int r = i >> 3, c = i & 7;
      uint4 v = *(const uint4*)(W + (long)(n0 + r) * K + k0 + c * 8);
      *(uint4*)&Ws[r * 64 + ((c ^ (r & 7)) << 3)] = v;
    }
    __syncthreads();
#pragma unroll
    for (int half = 0; half < 2; ++half) {
      int sw = ((half * 4 + quad) ^ (l15 & 7)) << 3;
      short8 af[4], bfr[NJ];
#pragma unroll
      for (int i = 0; i < 4; ++i) af[i] = *(short8*)&As[(wrow + i * 16 + l15) * 64 + sw];
#pragma unroll
      for (int j = 0; j < NJ; ++j) bfr[j] = *(short8*)&Ws[(wcol + j * 16 + l15) * 64 + sw];
#pragma unroll
      for (int i = 0; i < 4; ++i)
#pragma unroll
        for (int j = 0; j < NJ; ++j)
          acc[i][j] = __builtin_amdgcn_mfma_f32_16x16x32_bf16(af[i], bfr[j], acc[i][j], 0, 0, 0);
    }
    __syncthreads();
  }
#pragma unroll
  for (int i = 0; i < 4; ++i) {
#pragma unroll
    for (int j = 0; j < NJ; ++j) {
#pragma unroll
      for (int rg = 0; rg < 4; ++rg) {
        int m = m0 + wrow + i * 16 + quad * 4 + rg;
        int n = n0 + wcol + j * 16 + l15;
        float v = alpha * acc[i][j][rg];
        if (addend) v += addend[(long)m * ldc + n];
        if (OBF) ((ushort_t*)C)[(long)m * ldc + n] = f2us(v);
        else     ((float*)C)[(long)m * ldc + n] = v;
      }
    }
  }
}

// ---------------- Rq GEMM (bf16): Rq[(bh*1024+qo)][ri] = q . rel[min(ri,382)] ----------------
__global__ __launch_bounds__(256) void k_rq_b(const ushort_t* __restrict__ qb,
    const ushort_t* __restrict__ relB, bf16* __restrict__ Rq) {
  __shared__ ushort_t As[128 * 64];
  __shared__ ushort_t Ws[128 * 64];
  int t = threadIdx.x;
  int bh = blockIdx.z;
  const ushort_t* A = qb + (long)(bh >> 3) * Tc * Dc + (bh & 7) * 64;
  int m0 = blockIdx.y * 128, n0 = blockIdx.x * 128;
  int lane = t & 63, wv = t >> 6;
  int l15 = lane & 15, quad = lane >> 4;
  int wrow = (wv >> 1) * 64, wcol = (wv & 1) * 64;
  floatx4 acc[4][4];
#pragma unroll
  for (int i = 0; i < 4; ++i)
#pragma unroll
    for (int j = 0; j < 4; ++j) acc[i][j] = 0;
#pragma unroll
  for (int i = t; i < 128 * 8; i += 256) {
    int r = i >> 3, c = i & 7;
    uint4 v = *(const uint4*)(A + (long)(m0 + r) * Dc + c * 8);
    *(uint4*)&As[r * 64 + ((c ^ (r & 7)) << 3)] = v;
  }
#pragma unroll
  for (int i = t; i < 128 * 8; i += 256) {
    int r = i >> 3, c = i & 7;
    int wr = n0 + r; if (wr > 382) wr = 382;
    uint4 v = *(const uint4*)(relB + (long)wr * 64 + c * 8);
    *(uint4*)&Ws[r * 64 + ((c ^ (r & 7)) << 3)] = v;
  }
  __syncthreads();
#pragma unroll
  for (int half = 0; half < 2; ++half) {
    int sw = ((half * 4 + quad) ^ (l15 & 7)) << 3;
    short8 af[4], bfr[4];
#pragma unroll
    for (int i = 0; i < 4; ++i) af[i] = *(short8*)&As[(wrow + i * 16 + l15) * 64 + sw];
#pragma unroll
    for (int j = 0; j < 4; ++j) bfr[j] = *(short8*)&Ws[(wcol + j * 16 + l15) * 64 + sw];
#pragma unroll
    for (int i = 0; i < 4; ++i)
#pragma unroll
      for (int j = 0; j < 4; ++j)
        acc[i][j] = __builtin_amdgcn_mfma_f32_16x16x32_bf16(af[i], bfr[j], acc[i][j], 0, 0, 0);
  }
#pragma unroll
  for (int i = 0; i < 4; ++i)
#pragma unroll
    for (int j = 0; j < 4; ++j)
#pragma unroll
      for (int rg = 0; rg < 4; ++rg) {
        int m = m0 + wrow + i * 16 + quad * 4 + rg;
        int n = n0 + wcol + j * 16 + l15;
        Rq[((long)bh * Tc + m) * 384 + n] = __float2bfloat16(acc[i][j][rg]);
      }
}

// ---------------- MFMA flash attention (bf16 inputs) ----------------
template<bool INV>
__global__ __launch_bounds__(256) void k_attn_flash(const ushort_t* __restrict__ q,
    const ushort_t* __restrict__ kb, const ushort_t* __restrict__ vb,
    const bf16* __restrict__ Rq, const int* __restrict__ alen, ushort_t* __restrict__ out) {
  int qt = blockIdx.x, h = blockIdx.y, b = blockIdx.z;
  int len = alen[b];
  int q0 = qt * 64;
  if (INV) { if (q0 + 64 <= len) return; }
  else     { if (q0 >= len) return; }
  int nskip = max(len - q0, 0);
  int nvalid = min(len - q0, 64);
  int g = h >> 2;
  __shared__ __align__(16) ushort_t Qs[64 * 72];
  __shared__ __align__(16) ushort_t Ks[64 * 72];
  __shared__ __align__(16) ushort_t Vt[64 * 72];
  __shared__ __align__(16) ushort_t Ps[64 * 72];
  int t = threadIdx.x;
  int lane = t & 63, w = t >> 6;
  int l15 = lane & 15, quad = lane >> 4;
  int qw = w * 16;
  {
    int qi = t >> 2, du = (t & 3) * 16;
    const ushort_t* src = q + ((long)(b * Tc + q0 + qi)) * Dc + h * 64 + du;
    *(uint4*)&Qs[qi * 72 + du] = *(const uint4*)(src);
    *(uint4*)&Qs[qi * 72 + du + 8] = *(const uint4*)(src + 8);
  }
  float m_[4], l_[4], alpha[4];
  floatx4 acc[4];
#pragma unroll
  for (int r = 0; r < 4; ++r) { m_[r] = NEGB; l_[r] = 0.f; acc[r] = 0; }
  const ushort_t* Rqu = (const ushort_t*)Rq;
  long rqrow = (long)(b * 8 + h) * Tc + q0;
  const int NT = INV ? 18 : 3;
  for (int kt = 0; kt < NT; ++kt) {
    int ko0 = INV ? (kt * 64 - 128) : (q0 - 128 + kt * 64);
    __syncthreads();
    {
      int kj = t >> 2, du = (t & 3) * 16;
      int ko = ko0 + kj;
      if (ko >= 0) {
        long base = ((long)(b * Tc + ko)) * 128 + g * 64 + du;
        *(uint4*)&Ks[kj * 72 + du] = *(const uint4*)(kb + base);
        *(uint4*)&Ks[kj * 72 + du + 8] = *(const uint4*)(kb + base + 8);
        const ushort_t* vs = vb + base;
#pragma unroll
        for (int u = 0; u < 16; ++u) Vt[(du + u) * 72 + kj] = vs[u];
      } else {
        uint4 z = {0, 0, 0, 0};
        *(uint4*)&Ks[kj * 72 + du] = z;
        *(uint4*)&Ks[kj * 72 + du + 8] = z;
#pragma unroll
        for (int u = 0; u < 16; ++u) Vt[(du + u) * 72 + kj] = 0;
      }
    }
    __syncthreads();
    short8 aq0 = *(short8*)&Qs[(qw + l15) * 72 + quad * 8];
    short8 aq1 = *(short8*)&Qs[(qw + l15) * 72 + 32 + quad * 8];
    floatx4 s[4];
#pragma unroll
    for (int nt = 0; nt < 4; ++nt) {
      short8 bk0 = *(short8*)&Ks[(nt * 16 + l15) * 72 + quad * 8];
      short8 bk1 = *(short8*)&Ks[(nt * 16 + l15) * 72 + 32 + quad * 8];
      floatx4 z = {0.f, 0.f, 0.f, 0.f};
      z = __builtin_amdgcn_mfma_f32_16x16x32_bf16(aq0, bk0, z, 0, 0, 0);
      z = __builtin_amdgcn_mfma_f32_16x16x32_bf16(aq1, bk1, z, 0, 0, 0);
      s[nt] = z;
    }
#pragma unroll
    for (int nt = 0; nt < 4; ++nt) {
      int ko = ko0 + nt * 16 + l15;
      bool msk = (!INV) && (ko >= len);
#pragma unroll
      for (int r = 0; r < 4; ++r) {
        int qi = qw + quad * 4 + r;
        int dist = (q0 + qi) - ko;
        dist = min(max(dist, -(MPc - 1)), MPc - 1);
        float rv = us2f(Rqu[(rqrow + qi) * 384 + dist + 191]);
        s[nt][r] = msk ? NEGB : (s[nt][r] + rv);
      }
    }
#pragma unroll
    for (int r = 0; r < 4; ++r) {
      float mx = fmaxf(fmaxf(s[0][r], s[1][r]), fmaxf(s[2][r], s[3][r]));
#pragma unroll
      for (int o = 1; o < 16; o <<= 1) mx = fmaxf(mx, __shfl_xor(mx, o, 64));
      float mn = fmaxf(m_[r], mx);
      alpha[r] = __expf(m_[r] - mn);
      float p0 = __expf(s[0][r] - mn), p1 = __expf(s[1][r] - mn);
      float p2 = __expf(s[2][r] - mn), p3 = __expf(s[3][r] - mn);
      s[0][r] = p0; s[1][r] = p1; s[2][r] = p2; s[3][r] = p3;
      float ps = p0 + p1 + p2 + p3;
#pragma unroll
      for (int o = 1; o < 16; o <<= 1) ps += __shfl_xor(ps, o, 64);
      l_[r] = l_[r] * alpha[r] + ps;
      m_[r] = mn;
    }
#pragma unroll
    for (int nt = 0; nt < 4; ++nt)
#pragma unroll
      for (int r = 0; r < 4; ++r)
        Ps[(qw + quad * 4 + r) * 72 + nt * 16 + l15] = f2us(s[nt][r]);
#pragma unroll
    for (int j = 0; j < 4; ++j)
#pragma unroll
      for (int r = 0; r < 4; ++r) acc[j][r] *= alpha[r];
    short8 ap0 = *(short8*)&Ps[(qw + l15) * 72 + quad * 8];
    short8 ap1 = *(short8*)&Ps[(qw + l15) * 72 + 32 + quad * 8];
#pragma unroll
    for (int j = 0; j < 4; ++j) {
      short8 bv0 = *(short8*)&Vt[(j * 16 + l15) * 72 + quad * 8];
      short8 bv1 = *(short8*)&Vt[(j * 16 + l15) * 72 + 32 + quad * 8];
      acc[j] = __builtin_amdgcn_mfma_f32_16x16x32_bf16(ap0, bv0, acc[j], 0, 0, 0);
      acc[j] = __builtin_amdgcn_mfma_f32_16x16x32_bf16(ap1, bv1, acc[j], 0, 0, 0);
    }
  }
#pragma unroll
  for (int r = 0; r < 4; ++r) {
    int qi = qw + quad * 4 + r;
    bool wr = INV ? (qi >= nskip) : (qi < nvalid);
    if (wr) {
      float inv = 1.0f / l_[r];
#pragma unroll
      for (int j = 0; j < 4; ++j)
        out[((long)(b * Tc + q0 + qi)) * Dc + h * 64 + j * 16 + l15] = f2us(acc[j][r] * inv);
    }
  }
}

// ---------------- elementwise (bf16) ----------------
__global__ void k_glu(ushort_t* __restrict__ h, int n) {
  int i = blockIdx.x * 256 + threadIdx.x;
  if (i >= n) return;
  int r = i >> 9, j = i & 511;
  float a = us2f(h[(long)r * 1024 + j]), g = us2f(h[(long)r * 1024 + 512 + j]);
  h[(long)r * 1024 + j] = f2us(a * (1.0f / (1.0f + __expf(-g))));
}
__global__ void k_swiglu(ushort_t* __restrict__ h, int n) {
  int i = blockIdx.x * 256 + threadIdx.x;
  if (i >= n) return;
  int r = i >> 10, j = i & 1023;
  float a = us2f(h[(long)r * 2048 + j]), bb = us2f(h[(long)r * 2048 + 1024 + j]);
  h[(long)r * 2048 + j] = f2us((a / (1.0f + __expf(-a))) * bb);
}
__global__ void k_dwconv(const ushort_t* __restrict__ in, const ushort_t* __restrict__ dw,
                         ushort_t* __restrict__ out, int n) {
  int i = blockIdx.x * 256 + threadIdx.x;
  if (i >= n) return;
  int d = i & 511;
  int t = (i >> 9) & (Tc - 1);
  int b = i >> 19;
  float acc = 0.0f;
#pragma unroll
  for (int j = 0; j < 9; ++j) {
    int tt = t + j - 4;
    if (tt >= 0 && tt < Tc) acc += us2f(in[((long)(b * Tc + tt) << 10) + d]) * us2f(dw[d * 9 + j]);
  }
  out[i] = f2us(acc * (1.0f / (1.0f + __expf(-acc))));
}

extern "C" void kernel_launch(void* const* d_in, const int* in_sizes, int n_in,
                              void* d_out, int out_size, void* d_ws, size_t ws_size,
                              hipStream_t stream) {
  const void* x_in = d_in[0];
  const int*  alen = (const int*)d_in[1];
  const void* ln1w = d_in[2];
  const void* ln1b = d_in[3];
  const void* wq   = d_in[4];
  const void* wk   = d_in[5];
  const void* wv   = d_in[6];
  const void* wo   = d_in[7];
  const void* rel  = d_in[8];
  const void* ln2w = d_in[9];
  const void* ln2b = d_in[10];
  const void* pw1  = d_in[11];
  const void* dwv  = d_in[12];
  const void* pw2  = d_in[13];
  const void* ln3w = d_in[14];
  const void* ln3b = d_in[15];
  const void* w1   = d_in[16];
  const void* w2   = d_in[17];

  // ---- workspace layout (bytes) ----
  char* base = (char*)d_ws;
  int*      flag = (int*)base;                       // 256
  float*    xf   = (float*)(base + 256);             // 8 MB f32 residual
  float*    lnb  = (float*)(base + 256 + 8388608);   // 8 MB f32 LN out (addend)
  ushort_t* lnA  = (ushort_t*)(base + 16777472);     // 4 MB bf16 LN out (GEMM A)
  ushort_t* wbf  = (ushort_t*)(base + 20971776);     // 24,350,208 B bf16 weights
  char*     U    = base + 45321984;                  // phase union (35.7 MB)
  // attn phase
  ushort_t* qb = (ushort_t*)U;                       // 4 MB
  ushort_t* kb = (ushort_t*)(U + 4194304);           // 1 MB
  ushort_t* vb = (ushort_t*)(U + 5242880);           // 1 MB
  ushort_t* ab = (ushort_t*)(U + 6291456);           // 4 MB
  bf16*     Rq = (bf16*)(U + 10485760);              // 25,165,824 B
  // conv/ffn phase
  ushort_t* big = (ushort_t*)U;                      // up to 16 MB
  ushort_t* cb  = (ushort_t*)(U + 16777216);         // 4 MB
  size_t REQ = 45321984 + 16777216 + 4194304;        // conv needs cb beyond big region
  // (attn needs 45321984+35651584 = 80,973,568; take max)
  size_t REQ2 = 45321984 + 35651584;
  if (REQ2 > REQ) REQ = REQ2;
  if (ws_size < REQ) return;   // insufficient workspace (not expected: prior rounds prove ~89MB)

  // bf16 weight table offsets (elements)
  ushort_t* wqB  = wbf + 0;
  ushort_t* wkB  = wbf + 1048576;
  ushort_t* wvB  = wbf + 1310720;
  ushort_t* woB  = wbf + 1572864;
  ushort_t* relB = wbf + 2621440;
  ushort_t* pw1B = wbf + 2719488;
  ushort_t* dwB  = wbf + 4816640;
  ushort_t* pw2B = wbf + 4835072;
  ushort_t* w1B  = wbf + 5883648;
  ushort_t* w2B  = wbf + 10077952;

  k_detect<<<1, 256, 0, stream>>>(x_in, flag);
  k_in<<<(int)((NE + 255) / 256), 256, 0, stream>>>(x_in, xf, (int)NE, flag);
  k_w2b<<<4096, 256, 0, stream>>>(wq,  wqB,  1048576, flag);
  k_w2b<<<1024, 256, 0, stream>>>(wk,  wkB,  262144, flag);
  k_w2b<<<1024, 256, 0, stream>>>(wv,  wvB,  262144, flag);
  k_w2b<<<4096, 256, 0, stream>>>(wo,  woB,  1048576, flag);
  k_w2b<<<383,  256, 0, stream>>>(rel, relB, 98048, flag);
  k_w2b<<<8192, 256, 0, stream>>>(pw1, pw1B, 2097152, flag);
  k_w2b<<<72,   256, 0, stream>>>(dwv, dwB,  18432, flag);
  k_w2b<<<4096, 256, 0, stream>>>(pw2, pw2B, 1048576, flag);
  k_w2b<<<16384,256, 0, stream>>>(w1,  w1B,  4194304, flag);
  k_w2b<<<8192, 256, 0, stream>>>(w2,  w2B,  2097152, flag);

  for (int i = 0; i < 4; ++i) {
    long oLN = (long)i * Dc;
    // ---- attention ----
    k_ln<<<NBT, 256, 0, stream>>>(xf, ln1w, ln1b, oLN, lnb, lnA, flag);
    k_gemm_b<64, 128, true><<<dim3(4, 64), 256, 0, stream>>>(lnA, Dc, wqB + (long)i * 262144, qb, Dc, nullptr, 0.125f, 512);
    k_gemm_b<64, 64, true><<<dim3(2, 64), 256, 0, stream>>>(lnA, Dc, wkB + (long)i * 65536, kb, 128, nullptr, 1.0f, 512);
    k_gemm_b<64, 64, true><<<dim3(2, 64), 256, 0, stream>>>(lnA, Dc, wvB + (long)i * 65536, vb, 128, nullptr, 1.0f, 512);
    k_rq_b<<<dim3(3, 8, 32), 256, 0, stream>>>(qb, relB + (long)i * 24512, Rq);
    k_attn_flash<false><<<dim3(16, 8, 4), 256, 0, stream>>>(qb, kb, vb, Rq, alen, ab);
    k_attn_flash<true><<<dim3(16, 8, 4), 256, 0, stream>>>(qb, kb, vb, Rq, alen, ab);
    k_gemm_b<64, 128, false><<<dim3(4, 64), 256, 0, stream>>>(ab, Dc, woB + (long)i * 262144, xf, Dc, lnb, 1.0f, 512);

    // ---- conv ----
    k_ln<<<NBT, 256, 0, stream>>>(xf, ln2w, ln2b, oLN, lnb, lnA, flag);
    k_gemm_b<128, 128, true><<<dim3(8, 32), 256, 0, stream>>>(lnA, Dc, pw1B + (long)i * 524288, big, 1024, nullptr, 1.0f, 512);
    k_glu<<<NBT * 512 / 256, 256, 0, stream>>>(big, NBT * 512);
    k_dwconv<<<NBT * 512 / 256, 256, 0, stream>>>(big, dwB + (long)i * 4608, cb, NBT * 512);
    k_gemm_b<64, 128, false><<<dim3(4, 64), 256, 0, stream>>>(cb, Dc, pw2B + (long)i * 262144, xf, Dc, lnb, 1.0f, 512);

    // ---- ffn ----
    k_ln<<<NBT, 256, 0, stream>>>(xf, ln3w, ln3b, oLN, lnb, lnA, flag);
    k_gemm_b<128, 128, true><<<dim3(16, 32), 256, 0, stream>>>(lnA, Dc, w1B + (long)i * 1048576, big, 2048, nullptr, 1.0f, 512);
    k_swiglu<<<NBT * 1024 / 256, 256, 0, stream>>>(big, NBT * 1024);
    k_gemm_b<64, 128, false><<<dim3(4, 64), 256, 0, stream>>>(big, 2048, w2B + (long)i * 524288, xf, Dc, lnb, 1.0f, 1024);
  }

  k_out<<<(int)((NE + 255) / 256), 256, 0, stream>>>(xf, d_out, (int)NE, flag);
}